// Round 6
// baseline (355.449 us; speedup 1.0000x reference)
//
#include <hip/hip_runtime.h>
#include <hip/hip_bf16.h>
#include <math.h>

// Problem constants
#define BB 4
#define TT 2048
#define CC 1024
#define HH 16
#define DD 64
#define WW 256
#define MM (BB*TT)   // 8192 rows
#define NX (MM*CC)
#define NQ (3*CC*CC)
#define NP (CC*CC)

typedef __bf16 bf16x8 __attribute__((ext_vector_type(8)));
typedef __bf16 bf16x4 __attribute__((ext_vector_type(4)));
typedef float  f32x4  __attribute__((ext_vector_type(4)));

// async global->LDS 16B: LDS dest is wave-uniform base; HW adds lane*16
__device__ __forceinline__ void async_cp16(const void* g, void* l) {
  __builtin_amdgcn_global_load_lds(
      (const __attribute__((address_space(1))) void*)g,
      (__attribute__((address_space(3))) void*)l, 16, 0, 0);
}

__device__ __forceinline__ unsigned short f2bf(float v) {
  __hip_bfloat16 h = __float2bfloat16(v);
  return *(unsigned short*)&h;
}

// ---------------------------------------------------------------------------
// Convert weights fp32 -> bf16 (wqkvb, wprojb contiguous in ws)
// ---------------------------------------------------------------------------
__global__ void convert_w(const float* __restrict__ wq,
                          const float* __restrict__ wp,
                          __hip_bfloat16* __restrict__ dst) {
  int i = (blockIdx.x * 256 + threadIdx.x) * 4;
  const float* src; int off;
  if (i < NQ) { src = wq; off = i; }
  else        { src = wp; off = i - NQ; }
  float4 v = *(const float4*)(src + off);
  dst[i + 0] = __float2bfloat16(v.x);
  dst[i + 1] = __float2bfloat16(v.y);
  dst[i + 2] = __float2bfloat16(v.z);
  dst[i + 3] = __float2bfloat16(v.w);
}

// ---------------------------------------------------------------------------
// Convert + pack x into MFMA A-fragment-major layout:
//   Apk[((rt*32 + g)*64 + lane)*8], rt = row/16 (0..511), g = k/32 (0..31),
//   lane: l15 = row%16, quad = (k%32)/8. A wave's A-frag load is then ONE
//   coalesced 1KB global_load_dwordx4 (lane*16B contiguous).
// Block: 64 rows x 64 k, LDS transpose (both sides coalesced).
// ---------------------------------------------------------------------------
__global__ __launch_bounds__(256)
void pack_x(const float* __restrict__ x, unsigned short* __restrict__ Apk) {
  __shared__ __align__(16) unsigned short tile[64 * 72]; // stride 144B
  const int bm = blockIdx.x;   // 0..127
  const int bk = blockIdx.y;   // 0..15
  const int tid = threadIdx.x;
  const int tr = tid >> 4;          // 0..15
  const int tc = (tid & 15) * 4;    // 0..60
#pragma unroll
  for (int i = 0; i < 4; i++) {
    int row = i * 16 + tr;
    float4 v = *(const float4*)&x[(size_t)(bm * 64 + row) * 1024 + bk * 64 + tc];
    tile[row * 72 + tc + 0] = f2bf(v.x);
    tile[row * 72 + tc + 1] = f2bf(v.y);
    tile[row * 72 + tc + 2] = f2bf(v.z);
    tile[row * 72 + tc + 3] = f2bf(v.w);
  }
  __syncthreads();
  const int w = tid >> 6, lane = tid & 63;
  const int quad = lane >> 4, l15 = lane & 15;
#pragma unroll
  for (int f = 0; f < 2; f++) {
    bf16x8 fr = *(const bf16x8*)&tile[(w * 16 + l15) * 72 + f * 32 + quad * 8];
    *(bf16x8*)&Apk[(((size_t)(bm * 4 + w) * 32) + bk * 2 + f) * 512 + lane * 8] = fr;
  }
}

// ---------------------------------------------------------------------------
// QKV GEMM, restructured (round 6): 256x128 tile, 512 thr (8 waves, 4x2).
// A-fragments: DIRECT packed-global -> VGPR, coalesced, depth-1 prefetch,
// never couple to a barrier. B (weights): LDS, double-buffered 32 KB halves,
// BK=128, ONE barrier per stage issued AFTER next stage's DMA so the drain
// overlaps 64 MFMAs/wave. 1-D grid with XCD swizzle: each XCD owns 3
// n-panels x 32 m-blocks (B slice resident in its L2).
// Scatters to Qh/Kh/Vh [b*h][t][d], Q pre-scaled 0.125.
// ---------------------------------------------------------------------------
__global__ __launch_bounds__(512, 4)
void gemm_qkv(const unsigned short* __restrict__ Apk,
              const unsigned short* __restrict__ Bw,
              unsigned short* __restrict__ Qh,
              unsigned short* __restrict__ Kh,
              unsigned short* __restrict__ Vh) {
  __shared__ __align__(16) unsigned short Bs0[16 * 1024]; // 32 KB [kc16][col128][8]
  __shared__ __align__(16) unsigned short Bs1[16 * 1024];

  const int id   = blockIdx.x;
  const int xcd  = id & 7;
  const int slot = id >> 3;        // 0..95
  const int nloc = slot >> 5;      // 0..2
  const int mblk = slot & 31;      // 0..31
  const int n0 = (xcd * 3 + nloc) * 128;
  const int m0 = mblk * 256;

  const int tid  = threadIdx.x;
  const int w    = tid >> 6;       // 0..7
  const int lane = tid & 63;
  const int quad = lane >> 4;
  const int l15  = lane & 15;
  const int wm = w & 3;            // 4 row-blocks of 64
  const int wn = w >> 2;           // 2 col-blocks of 64

  f32x4 acc[4][4];
#pragma unroll
  for (int i = 0; i < 4; i++)
#pragma unroll
    for (int j = 0; j < 4; j++) acc[i][j] = (f32x4)0.0f;

  // packed-A base for this wave: frag(tm,g) at abase + (tm*32 + g)*512
  const unsigned short* abase =
      Apk + ((size_t)((m0 >> 4) + wm * 4) * 32) * 512 + lane * 8;

  auto stageB = [&](int k0, unsigned short* bs) {
#pragma unroll
    for (int i = 0; i < 4; i++) {
      int idx  = w + 8 * i;        // 0..31
      int kc   = idx >> 1;         // 0..15
      int half = idx & 1;
      async_cp16(Bw + (size_t)(n0 + half * 64 + lane) * 1024 + k0 + kc * 8,
                 &bs[kc * 1024 + half * 512]);
    }
  };

  bf16x8 Af[2][4];
  auto loadA = [&](int g, bf16x8* fr) {
#pragma unroll
    for (int tm = 0; tm < 4; tm++)
      fr[tm] = *(const bf16x8*)(abase + ((size_t)(tm * 32 + g)) * 512);
  };

  loadA(0, Af[0]);
  stageB(0, Bs0);
  __syncthreads();

#pragma unroll
  for (int s = 0; s < 8; s++) {
    const unsigned short* bs = (s & 1) ? Bs1 : Bs0;
    if (s + 1 < 8) stageB((s + 1) * 128, (s & 1) ? Bs0 : Bs1);
#pragma unroll
    for (int sub = 0; sub < 4; sub++) {
      const int g = s * 4 + sub;
      if (g + 1 < 32) loadA(g + 1, Af[(g + 1) & 1]);
      const bf16x8* af = Af[g & 1];
      bf16x8 bfv[4];
#pragma unroll
      for (int tn = 0; tn < 4; tn++)
        bfv[tn] = *(const bf16x8*)
            &bs[(sub * 4 + quad) * 1024 + (wn * 64 + tn * 16 + l15) * 8];
#pragma unroll
      for (int tm = 0; tm < 4; tm++)
#pragma unroll
        for (int tn = 0; tn < 4; tn++)
          acc[tm][tn] = __builtin_amdgcn_mfma_f32_16x16x32_bf16(
              af[tm], bfv[tn], acc[tm][tn], 0, 0, 0);
    }
    __syncthreads();   // waves done with bs; drain overlapped next stage's DMA
  }

  // scatter qkv: col -> (which, head, d); row -> (b, t)
#pragma unroll
  for (int tm = 0; tm < 4; tm++)
#pragma unroll
    for (int tn = 0; tn < 4; tn++) {
      int colb = n0 + wn * 64 + tn * 16;     // 16-aligned: t3,h uniform
      int t3 = colb >> 10;
      int hh = (colb >> 6) & 15;
      int dd = (colb & 63) + l15;
      unsigned short* dst = (t3 == 0) ? Qh : ((t3 == 1) ? Kh : Vh);
      float sc = (t3 == 0) ? 0.125f : 1.0f;  // 1/sqrt(64), exact
#pragma unroll
      for (int r = 0; r < 4; r++) {
        int row = m0 + wm * 64 + tm * 16 + quad * 4 + r;
        int b = row >> 11, tt = row & 2047;
        dst[((size_t)((b * 16 + hh) * 2048 + tt)) * 64 + dd] =
            f2bf(acc[tm][tn][r] * sc);
      }
    }
}

// ---------------------------------------------------------------------------
// Proj GEMM: r2-proven 128x128 tile, BK=64, 2-barrier loop, fp32 output.
// ---------------------------------------------------------------------------
__global__ __launch_bounds__(256, 2)
void gemm_proj(const unsigned short* __restrict__ A,
               const unsigned short* __restrict__ Bw,
               float* __restrict__ Co) {
  __shared__ __align__(16) unsigned short As[8 * 1024]; // [kc][128 rows][8]
  __shared__ __align__(16) unsigned short Bs[8 * 1024];

  const int tid  = threadIdx.x;
  const int w    = tid >> 6;
  const int lane = tid & 63;
  const int quad = lane >> 4;
  const int l15  = lane & 15;
  const int m0 = blockIdx.x * 128;
  const int n0 = blockIdx.y * 128;
  const int wm = w & 1;
  const int wn = w >> 1;

  f32x4 acc[4][4];
#pragma unroll
  for (int i = 0; i < 4; i++)
#pragma unroll
    for (int j = 0; j < 4; j++) acc[i][j] = (f32x4)0.0f;

  for (int k0 = 0; k0 < 1024; k0 += 64) {
#pragma unroll
    for (int i = 0; i < 4; i++) {
      int idx = w + 4 * i;
      int kc  = idx >> 1;
      int mh  = idx & 1;
      async_cp16(A + (size_t)(m0 + mh * 64 + lane) * 1024 + k0 + kc * 8,
                 &As[kc * 1024 + mh * 512]);
      async_cp16(Bw + (size_t)(n0 + mh * 64 + lane) * 1024 + k0 + kc * 8,
                 &Bs[kc * 1024 + mh * 512]);
    }
    __syncthreads();

#pragma unroll
    for (int ks = 0; ks < 2; ks++) {
      bf16x8 af[4], bfv[4];
      int kc = ks * 4 + quad;
#pragma unroll
      for (int t = 0; t < 4; t++) {
        af[t]  = *(const bf16x8*)&As[kc * 1024 + (wm * 64 + t * 16 + l15) * 8];
        bfv[t] = *(const bf16x8*)&Bs[kc * 1024 + (wn * 64 + t * 16 + l15) * 8];
      }
#pragma unroll
      for (int tm = 0; tm < 4; tm++)
#pragma unroll
        for (int tn = 0; tn < 4; tn++)
          acc[tm][tn] = __builtin_amdgcn_mfma_f32_16x16x32_bf16(
              af[tm], bfv[tn], acc[tm][tn], 0, 0, 0);
    }
    __syncthreads();
  }

#pragma unroll
  for (int tm = 0; tm < 4; tm++)
#pragma unroll
    for (int tn = 0; tn < 4; tn++)
#pragma unroll
      for (int r = 0; r < 4; r++) {
        int row = m0 + wm * 64 + tm * 16 + quad * 4 + r;
        int col = n0 + wn * 64 + tn * 16 + l15;
        Co[(size_t)row * 1024 + col] = acc[tm][tn][r];
      }
}

// ---------------------------------------------------------------------------
// Vh [bh][t][d] -> Vt chunk-blocked [bh][tc=32][d=64][tin=64]
// ---------------------------------------------------------------------------
__global__ __launch_bounds__(256)
void transpose_v(const unsigned short* __restrict__ Vh,
                 unsigned short* __restrict__ Vt) {
  __shared__ __align__(16) unsigned short tile[64 * 72]; // row stride 144B
  const int tid = threadIdx.x;
  const int tc = blockIdx.x, bh = blockIdx.y;
  const unsigned short* src = Vh + ((size_t)bh * 2048 + (size_t)tc * 64) * 64;
  for (int i = tid; i < 512; i += 256) {
    int r = i >> 3, ds = (i & 7) * 8;
    *(uint4*)&tile[r * 72 + ds] = *(const uint4*)&src[(size_t)r * 64 + ds];
  }
  __syncthreads();
  unsigned short* dst = Vt + (size_t)(bh * 32 + tc) * 4096;
  for (int i = tid; i < 512; i += 256) {
    int d = i >> 3, ts = (i & 7) * 8;
    unsigned int w0 = tile[(ts + 0) * 72 + d] | ((unsigned int)tile[(ts + 1) * 72 + d] << 16);
    unsigned int w1 = tile[(ts + 2) * 72 + d] | ((unsigned int)tile[(ts + 3) * 72 + d] << 16);
    unsigned int w2 = tile[(ts + 4) * 72 + d] | ((unsigned int)tile[(ts + 5) * 72 + d] << 16);
    unsigned int w3 = tile[(ts + 6) * 72 + d] | ((unsigned int)tile[(ts + 7) * 72 + d] << 16);
    uint4 o; o.x = w0; o.y = w1; o.z = w2; o.w = w3;
    *(uint4*)&dst[(size_t)d * 64 + ts] = o;
  }
}

// ---------------------------------------------------------------------------
// MFMA sliding-window flash attention (unchanged from round 2).
// ---------------------------------------------------------------------------
__global__ __launch_bounds__(256, 2)
void attn_mfma(const unsigned short* __restrict__ Qh,
               const unsigned short* __restrict__ Kh,
               const unsigned short* __restrict__ Vt,
               __hip_bfloat16* __restrict__ y) {
  __shared__ __align__(16) unsigned short Qs[8 * 512]; // [kc_d][q 64][8]
  __shared__ __align__(16) unsigned short Ks[8 * 512]; // [kc_d][j 64][8]
  __shared__ __align__(16) unsigned short Vs[8 * 512]; // [kc_j][d 64][8]
  __shared__ __align__(16) unsigned short Ps[64 * 68]; // [q][j], row 136B

  const int tid  = threadIdx.x;
  const int w    = tid >> 6;
  const int lane = tid & 63;
  const int quad = lane >> 4;
  const int l15  = lane & 15;
  const int q0 = blockIdx.x * 64;
  const int bh = blockIdx.y;            // b*16+h

  const unsigned short* Qg = Qh + ((size_t)bh * 2048 + q0) * 64;

#pragma unroll
  for (int i = 0; i < 2; i++) {
    int kc = w * 2 + i;
    async_cp16(Qg + (size_t)lane * 64 + kc * 8, &Qs[kc * 512]);
  }

  f32x4 Oacc[4];
  float m_[4], l_[4];
#pragma unroll
  for (int t = 0; t < 4; t++) { Oacc[t] = (f32x4)0.0f; }
#pragma unroll
  for (int r = 0; r < 4; r++) { m_[r] = -__builtin_inff(); l_[r] = 0.0f; }

  for (int c = 0; c < 5; c++) {
    const int sc = q0 - 256 + c * 64;   // block-uniform
    if (sc < 0) continue;
    __syncthreads();                    // prior chunk's Ks/Vs reads complete
    const unsigned short* Kg = Kh + ((size_t)bh * 2048 + sc) * 64;
    const unsigned short* Vg = Vt + ((size_t)(bh * 32) + (sc >> 6)) * 4096;
#pragma unroll
    for (int i = 0; i < 2; i++) {
      int kc = w * 2 + i;
      async_cp16(Kg + (size_t)lane * 64 + kc * 8, &Ks[kc * 512]);
      async_cp16(Vg + (size_t)lane * 64 + kc * 8, &Vs[kc * 512]);
    }
    __syncthreads();                    // drains vmcnt -> staging visible

    // ---- S = Q K^T
    f32x4 S[4];
#pragma unroll
    for (int tn = 0; tn < 4; tn++) S[tn] = (f32x4)0.0f;
#pragma unroll
    for (int ks = 0; ks < 2; ks++) {
      int kc = ks * 4 + quad;
      bf16x8 aq = *(const bf16x8*)&Qs[kc * 512 + (w * 16 + l15) * 8];
#pragma unroll
      for (int tn = 0; tn < 4; tn++) {
        bf16x8 bk = *(const bf16x8*)&Ks[kc * 512 + (tn * 16 + l15) * 8];
        S[tn] = __builtin_amdgcn_mfma_f32_16x16x32_bf16(aq, bk, S[tn], 0, 0, 0);
      }
    }

    // ---- mask (only first/last chunk partial)
    const int qb = q0 + w * 16 + quad * 4;  // + r
    if (c == 0) {
#pragma unroll
      for (int tn = 0; tn < 4; tn++) {
        int j = sc + tn * 16 + l15;
#pragma unroll
        for (int r = 0; r < 4; r++)
          if (qb + r > j + (WW - 1)) S[tn][r] = -__builtin_inff();
      }
    } else if (sc == q0) {
#pragma unroll
      for (int tn = 0; tn < 4; tn++) {
        int j = sc + tn * 16 + l15;
#pragma unroll
        for (int r = 0; r < 4; r++)
          if (j > qb + r) S[tn][r] = -__builtin_inff();
      }
    }

    // ---- online softmax
    float mx[4], al[4], em[4], ps[4];
#pragma unroll
    for (int r = 0; r < 4; r++)
      mx[r] = fmaxf(fmaxf(S[0][r], S[1][r]), fmaxf(S[2][r], S[3][r]));
#pragma unroll
    for (int off = 1; off < 16; off <<= 1)
#pragma unroll
      for (int r = 0; r < 4; r++) mx[r] = fmaxf(mx[r], __shfl_xor(mx[r], off));
#pragma unroll
    for (int r = 0; r < 4; r++) {
      float mn = fmaxf(m_[r], mx[r]);
      em[r] = (mn == -__builtin_inff()) ? 0.0f : mn;
      al[r] = __expf(m_[r] - em[r]);
      m_[r] = mn;
    }
#pragma unroll
    for (int tn = 0; tn < 4; tn++)
#pragma unroll
      for (int r = 0; r < 4; r++)
        S[tn][r] = __expf(S[tn][r] - em[r]);
#pragma unroll
    for (int r = 0; r < 4; r++)
      ps[r] = (S[0][r] + S[1][r]) + (S[2][r] + S[3][r]);
#pragma unroll
    for (int off = 1; off < 16; off <<= 1)
#pragma unroll
      for (int r = 0; r < 4; r++) ps[r] += __shfl_xor(ps[r], off);
#pragma unroll
    for (int r = 0; r < 4; r++) l_[r] = l_[r] * al[r] + ps[r];

#pragma unroll
    for (int td = 0; td < 4; td++)
#pragma unroll
      for (int r = 0; r < 4; r++) Oacc[td][r] *= al[r];

    // ---- P -> LDS (bf16)
#pragma unroll
    for (int tn = 0; tn < 4; tn++)
#pragma unroll
      for (int r = 0; r < 4; r++)
        Ps[(w * 16 + quad * 4 + r) * 68 + tn * 16 + l15] = f2bf(S[tn][r]);
    asm volatile("s_waitcnt lgkmcnt(0)" ::: "memory");

    // ---- O += P V
#pragma unroll
    for (int ks = 0; ks < 2; ks++) {
      int off = (w * 16 + l15) * 68 + ks * 32 + quad * 8;
      bf16x4 plo = *(const bf16x4*)&Ps[off];
      bf16x4 phi = *(const bf16x4*)&Ps[off + 4];
      bf16x8 ap = __builtin_shufflevector(plo, phi, 0, 1, 2, 3, 4, 5, 6, 7);
      int kc = ks * 4 + quad;
#pragma unroll
      for (int td = 0; td < 4; td++) {
        bf16x8 bv = *(const bf16x8*)&Vs[kc * 512 + (td * 16 + l15) * 8];
        Oacc[td] = __builtin_amdgcn_mfma_f32_16x16x32_bf16(ap, bv, Oacc[td], 0, 0, 0);
      }
    }
  }

  // ---- epilogue
  const int b = bh >> 4, h = bh & 15;
  float inv[4];
#pragma unroll
  for (int r = 0; r < 4; r++) inv[r] = 1.0f / l_[r];
#pragma unroll
  for (int td = 0; td < 4; td++)
#pragma unroll
    for (int r = 0; r < 4; r++) {
      int q = q0 + w * 16 + quad * 4 + r;
      y[((size_t)(b * 2048 + q)) * 1024 + h * 64 + td * 16 + l15] =
          __float2bfloat16(Oacc[td][r] * inv[r]);
    }
}

// ---------------------------------------------------------------------------
extern "C" void kernel_launch(void* const* d_in, const int* in_sizes, int n_in,
                              void* d_out, int out_size, void* d_ws, size_t ws_size,
                              hipStream_t stream) {
  const float* x     = (const float*)d_in[0];
  const float* wqkv  = (const float*)d_in[1];
  const float* wproj = (const float*)d_in[2];
  float* out = (float*)d_out;

  char* ws = (char*)d_ws;
  // [0,16M)   Apk (packed x; dead after QKV gemm) -> reused as Vt
  // [16,22M)  Wqkv bf16   [22,24M) Wproj bf16  (contiguous for convert_w)
  // [24,40M)  Qh   [40,56M) Kh   [56,72M) Vh   [72,88M) y bf16
  unsigned short* apk    = (unsigned short*)(ws);
  unsigned short* vtb    = (unsigned short*)(ws);  // aliases Apk (after gemm)
  unsigned short* wqkvb  = (unsigned short*)(ws + (size_t)16 * 1024 * 1024);
  unsigned short* wprojb = (unsigned short*)(ws + (size_t)22 * 1024 * 1024);
  unsigned short* qh     = (unsigned short*)(ws + (size_t)24 * 1024 * 1024);
  unsigned short* kh     = (unsigned short*)(ws + (size_t)40 * 1024 * 1024);
  unsigned short* vh     = (unsigned short*)(ws + (size_t)56 * 1024 * 1024);
  unsigned short* yb     = (unsigned short*)(ws + (size_t)72 * 1024 * 1024);

  convert_w<<<(NQ + NP) / 1024, 256, 0, stream>>>(
      wqkv, wproj, (__hip_bfloat16*)wqkvb);
  pack_x<<<dim3(128, 16), 256, 0, stream>>>(x, apk);

  // qkv = x @ Wqkv^T, scattered to head-major Q/K/V (Q pre-scaled)
  gemm_qkv<<<768, 512, 0, stream>>>(apk, wqkvb, qh, kh, vh);

  // V -> chunk-blocked transpose (into Apk region, now dead)
  transpose_v<<<dim3(32, 64), 256, 0, stream>>>(vh, vtb);

  // attention
  attn_mfma<<<dim3(TT / 64, BB * HH), 256, 0, stream>>>(
      qh, kh, vtb, (__hip_bfloat16*)yb);

  // out = y @ Wproj^T -> fp32
  gemm_proj<<<dim3(MM / 128, CC / 128), 256, 0, stream>>>(
      yb, wprojb, out);
}

// Round 7
// 254.036 us; speedup vs baseline: 1.3992x; 1.3992x over previous
//
#include <hip/hip_runtime.h>
#include <hip/hip_bf16.h>
#include <math.h>

// Problem constants
#define BB 4
#define TT 2048
#define CC 1024
#define HH 16
#define DD 64
#define WW 256
#define MM (BB*TT)   // 8192 rows
#define NX (MM*CC)
#define NQ (3*CC*CC)
#define NP (CC*CC)

typedef __bf16 bf16x8 __attribute__((ext_vector_type(8)));
typedef __bf16 bf16x4 __attribute__((ext_vector_type(4)));
typedef float  f32x4  __attribute__((ext_vector_type(4)));

// async global->LDS 16B: LDS dest is wave-uniform base; HW adds lane*16
__device__ __forceinline__ void async_cp16(const void* g, void* l) {
  __builtin_amdgcn_global_load_lds(
      (const __attribute__((address_space(1))) void*)g,
      (__attribute__((address_space(3))) void*)l, 16, 0, 0);
}

__device__ __forceinline__ unsigned short f2bf(float v) {
  __hip_bfloat16 h = __float2bfloat16(v);
  return *(unsigned short*)&h;
}

// ---------------------------------------------------------------------------
// Convert weights fp32 -> bf16 (wqkvb, wprojb contiguous in ws)
// ---------------------------------------------------------------------------
__global__ void convert_w(const float* __restrict__ wq,
                          const float* __restrict__ wp,
                          __hip_bfloat16* __restrict__ dst) {
  int i = (blockIdx.x * 256 + threadIdx.x) * 4;
  const float* src; int off;
  if (i < NQ) { src = wq; off = i; }
  else        { src = wp; off = i - NQ; }
  float4 v = *(const float4*)(src + off);
  dst[i + 0] = __float2bfloat16(v.x);
  dst[i + 1] = __float2bfloat16(v.y);
  dst[i + 2] = __float2bfloat16(v.z);
  dst[i + 3] = __float2bfloat16(v.w);
}

// ---------------------------------------------------------------------------
// Convert + pack x into MFMA A-fragment-major layout:
//   Apk[((rt*32 + g)*64 + lane)*8], rt = row/16 (0..511), g = k/32 (0..31),
//   lane: l15 = row%16, quad = (k%32)/8. A wave's A-frag load is then ONE
//   coalesced 1KB global_load_dwordx4 (lane*16B contiguous).
// ---------------------------------------------------------------------------
__global__ __launch_bounds__(256)
void pack_x(const float* __restrict__ x, unsigned short* __restrict__ Apk) {
  __shared__ __align__(16) unsigned short tile[64 * 72]; // stride 144B
  const int bm = blockIdx.x;   // 0..127
  const int bk = blockIdx.y;   // 0..15
  const int tid = threadIdx.x;
  const int tr = tid >> 4;          // 0..15
  const int tc = (tid & 15) * 4;    // 0..60
#pragma unroll
  for (int i = 0; i < 4; i++) {
    int row = i * 16 + tr;
    float4 v = *(const float4*)&x[(size_t)(bm * 64 + row) * 1024 + bk * 64 + tc];
    tile[row * 72 + tc + 0] = f2bf(v.x);
    tile[row * 72 + tc + 1] = f2bf(v.y);
    tile[row * 72 + tc + 2] = f2bf(v.z);
    tile[row * 72 + tc + 3] = f2bf(v.w);
  }
  __syncthreads();
  const int w = tid >> 6, lane = tid & 63;
  const int quad = lane >> 4, l15 = lane & 15;
#pragma unroll
  for (int f = 0; f < 2; f++) {
    bf16x8 fr = *(const bf16x8*)&tile[(w * 16 + l15) * 72 + f * 32 + quad * 8];
    *(bf16x8*)&Apk[(((size_t)(bm * 4 + w) * 32) + bk * 2 + f) * 512 + lane * 8] = fr;
  }
}

// ---------------------------------------------------------------------------
// QKV GEMM (round 7 = round 6 structure, spill-fixed):
//  - __launch_bounds__(512,2): 256 regs/wave -> acc(64) + Af[3](48) + bfv(16)
//    + addressing fit WITHOUT scratch spill (r6's 328 MB WRITE was spill).
//  - A: direct packed-global -> VGPR, coalesced 1KB/wave-instr, depth-2
//    prefetch (covers ~2 sub-iters of latency), never couples to a barrier.
//  - B: LDS double-buffer, BK=128, one barrier per stage, stage issued a
//    full compute-phase (~2.5k cyc) ahead of its drain.
//  - Swizzle: xcd = id&7; slot mblk-major so the 3 n-panels sharing an
//    A-tile run adjacently on one XCD (A re-reads hit L2).
// ---------------------------------------------------------------------------
__global__ __launch_bounds__(512, 2)
void gemm_qkv(const unsigned short* __restrict__ Apk,
              const unsigned short* __restrict__ Bw,
              unsigned short* __restrict__ Qh,
              unsigned short* __restrict__ Kh,
              unsigned short* __restrict__ Vh) {
  __shared__ __align__(16) unsigned short Bs0[16 * 1024]; // 32 KB [kc16][col128][8]
  __shared__ __align__(16) unsigned short Bs1[16 * 1024];

  const int id   = blockIdx.x;
  const int xcd  = id & 7;
  const int slot = id >> 3;        // 0..95
  const int mblk = slot / 3;       // 0..31  (mblk-major: 3 n-panels adjacent)
  const int nloc = slot % 3;       // 0..2
  const int n0 = (xcd * 3 + nloc) * 128;
  const int m0 = mblk * 256;

  const int tid  = threadIdx.x;
  const int w    = tid >> 6;       // 0..7
  const int lane = tid & 63;
  const int quad = lane >> 4;
  const int l15  = lane & 15;
  const int wm = w & 3;            // 4 row-blocks of 64
  const int wn = w >> 2;           // 2 col-blocks of 64

  f32x4 acc[4][4];
#pragma unroll
  for (int i = 0; i < 4; i++)
#pragma unroll
    for (int j = 0; j < 4; j++) acc[i][j] = (f32x4)0.0f;

  // packed-A base for this wave: frag(tm,g) at abase + (tm*32 + g)*512
  const unsigned short* abase =
      Apk + ((size_t)((m0 >> 4) + wm * 4) * 32) * 512 + lane * 8;

  auto stageB = [&](int k0, unsigned short* bs) {
#pragma unroll
    for (int i = 0; i < 4; i++) {
      int idx  = w + 8 * i;        // 0..31
      int kc   = idx >> 1;         // 0..15
      int half = idx & 1;
      async_cp16(Bw + (size_t)(n0 + half * 64 + lane) * 1024 + k0 + kc * 8,
                 &bs[kc * 1024 + half * 512]);
    }
  };

  bf16x8 Af[3][4];                 // depth-2 prefetch ring
  auto loadA = [&](int g, bf16x8* fr) {
#pragma unroll
    for (int tm = 0; tm < 4; tm++)
      fr[tm] = *(const bf16x8*)(abase + ((size_t)(tm * 32 + g)) * 512);
  };

  loadA(0, Af[0]);
  loadA(1, Af[1]);
  stageB(0, Bs0);
  __syncthreads();

#pragma unroll
  for (int s = 0; s < 8; s++) {
    const unsigned short* bs = (s & 1) ? Bs1 : Bs0;
    if (s + 1 < 8) stageB((s + 1) * 128, (s & 1) ? Bs0 : Bs1);
#pragma unroll
    for (int sub = 0; sub < 4; sub++) {
      const int g = s * 4 + sub;
      if (g + 2 < 32) loadA(g + 2, Af[(g + 2) % 3]);
      const bf16x8* af = Af[g % 3];
      bf16x8 bfv[4];
#pragma unroll
      for (int tn = 0; tn < 4; tn++)
        bfv[tn] = *(const bf16x8*)
            &bs[(sub * 4 + quad) * 1024 + (wn * 64 + tn * 16 + l15) * 8];
#pragma unroll
      for (int tm = 0; tm < 4; tm++)
#pragma unroll
        for (int tn = 0; tn < 4; tn++)
          acc[tm][tn] = __builtin_amdgcn_mfma_f32_16x16x32_bf16(
              af[tm], bfv[tn], acc[tm][tn], 0, 0, 0);
    }
    __syncthreads();   // waves done with bs; drain overlapped next stage's DMA
  }

  // scatter qkv: col -> (which, head, d); row -> (b, t)
#pragma unroll
  for (int tm = 0; tm < 4; tm++)
#pragma unroll
    for (int tn = 0; tn < 4; tn++) {
      int colb = n0 + wn * 64 + tn * 16;     // 16-aligned: t3,h uniform
      int t3 = colb >> 10;
      int hh = (colb >> 6) & 15;
      int dd = (colb & 63) + l15;
      unsigned short* dst = (t3 == 0) ? Qh : ((t3 == 1) ? Kh : Vh);
      float sc = (t3 == 0) ? 0.125f : 1.0f;  // 1/sqrt(64), exact
#pragma unroll
      for (int r = 0; r < 4; r++) {
        int row = m0 + wm * 64 + tm * 16 + quad * 4 + r;
        int b = row >> 11, tt = row & 2047;
        dst[((size_t)((b * 16 + hh) * 2048 + tt)) * 64 + dd] =
            f2bf(acc[tm][tn][r] * sc);
      }
    }
}

// ---------------------------------------------------------------------------
// Proj GEMM: r2-proven 128x128 tile, BK=64, 2-barrier loop, fp32 output.
// ---------------------------------------------------------------------------
__global__ __launch_bounds__(256, 2)
void gemm_proj(const unsigned short* __restrict__ A,
               const unsigned short* __restrict__ Bw,
               float* __restrict__ Co) {
  __shared__ __align__(16) unsigned short As[8 * 1024]; // [kc][128 rows][8]
  __shared__ __align__(16) unsigned short Bs[8 * 1024];

  const int tid  = threadIdx.x;
  const int w    = tid >> 6;
  const int lane = tid & 63;
  const int quad = lane >> 4;
  const int l15  = lane & 15;
  const int m0 = blockIdx.x * 128;
  const int n0 = blockIdx.y * 128;
  const int wm = w & 1;
  const int wn = w >> 1;

  f32x4 acc[4][4];
#pragma unroll
  for (int i = 0; i < 4; i++)
#pragma unroll
    for (int j = 0; j < 4; j++) acc[i][j] = (f32x4)0.0f;

  for (int k0 = 0; k0 < 1024; k0 += 64) {
#pragma unroll
    for (int i = 0; i < 4; i++) {
      int idx = w + 4 * i;
      int kc  = idx >> 1;
      int mh  = idx & 1;
      async_cp16(A + (size_t)(m0 + mh * 64 + lane) * 1024 + k0 + kc * 8,
                 &As[kc * 1024 + mh * 512]);
      async_cp16(Bw + (size_t)(n0 + mh * 64 + lane) * 1024 + k0 + kc * 8,
                 &Bs[kc * 1024 + mh * 512]);
    }
    __syncthreads();

#pragma unroll
    for (int ks = 0; ks < 2; ks++) {
      bf16x8 af[4], bfv[4];
      int kc = ks * 4 + quad;
#pragma unroll
      for (int t = 0; t < 4; t++) {
        af[t]  = *(const bf16x8*)&As[kc * 1024 + (wm * 64 + t * 16 + l15) * 8];
        bfv[t] = *(const bf16x8*)&Bs[kc * 1024 + (wn * 64 + t * 16 + l15) * 8];
      }
#pragma unroll
      for (int tm = 0; tm < 4; tm++)
#pragma unroll
        for (int tn = 0; tn < 4; tn++)
          acc[tm][tn] = __builtin_amdgcn_mfma_f32_16x16x32_bf16(
              af[tm], bfv[tn], acc[tm][tn], 0, 0, 0);
    }
    __syncthreads();
  }

#pragma unroll
  for (int tm = 0; tm < 4; tm++)
#pragma unroll
    for (int tn = 0; tn < 4; tn++)
#pragma unroll
      for (int r = 0; r < 4; r++) {
        int row = m0 + wm * 64 + tm * 16 + quad * 4 + r;
        int col = n0 + wn * 64 + tn * 16 + l15;
        Co[(size_t)row * 1024 + col] = acc[tm][tn][r];
      }
}

// ---------------------------------------------------------------------------
// Vh [bh][t][d] -> Vt chunk-blocked [bh][tc=32][d=64][tin=64]
// ---------------------------------------------------------------------------
__global__ __launch_bounds__(256)
void transpose_v(const unsigned short* __restrict__ Vh,
                 unsigned short* __restrict__ Vt) {
  __shared__ __align__(16) unsigned short tile[64 * 72]; // row stride 144B
  const int tid = threadIdx.x;
  const int tc = blockIdx.x, bh = blockIdx.y;
  const unsigned short* src = Vh + ((size_t)bh * 2048 + (size_t)tc * 64) * 64;
  for (int i = tid; i < 512; i += 256) {
    int r = i >> 3, ds = (i & 7) * 8;
    *(uint4*)&tile[r * 72 + ds] = *(const uint4*)&src[(size_t)r * 64 + ds];
  }
  __syncthreads();
  unsigned short* dst = Vt + (size_t)(bh * 32 + tc) * 4096;
  for (int i = tid; i < 512; i += 256) {
    int d = i >> 3, ts = (i & 7) * 8;
    unsigned int w0 = tile[(ts + 0) * 72 + d] | ((unsigned int)tile[(ts + 1) * 72 + d] << 16);
    unsigned int w1 = tile[(ts + 2) * 72 + d] | ((unsigned int)tile[(ts + 3) * 72 + d] << 16);
    unsigned int w2 = tile[(ts + 4) * 72 + d] | ((unsigned int)tile[(ts + 5) * 72 + d] << 16);
    unsigned int w3 = tile[(ts + 6) * 72 + d] | ((unsigned int)tile[(ts + 7) * 72 + d] << 16);
    uint4 o; o.x = w0; o.y = w1; o.z = w2; o.w = w3;
    *(uint4*)&dst[(size_t)d * 64 + ts] = o;
  }
}

// ---------------------------------------------------------------------------
// MFMA sliding-window flash attention (unchanged from round 2).
// ---------------------------------------------------------------------------
__global__ __launch_bounds__(256, 2)
void attn_mfma(const unsigned short* __restrict__ Qh,
               const unsigned short* __restrict__ Kh,
               const unsigned short* __restrict__ Vt,
               __hip_bfloat16* __restrict__ y) {
  __shared__ __align__(16) unsigned short Qs[8 * 512]; // [kc_d][q 64][8]
  __shared__ __align__(16) unsigned short Ks[8 * 512]; // [kc_d][j 64][8]
  __shared__ __align__(16) unsigned short Vs[8 * 512]; // [kc_j][d 64][8]
  __shared__ __align__(16) unsigned short Ps[64 * 68]; // [q][j], row 136B

  const int tid  = threadIdx.x;
  const int w    = tid >> 6;
  const int lane = tid & 63;
  const int quad = lane >> 4;
  const int l15  = lane & 15;
  const int q0 = blockIdx.x * 64;
  const int bh = blockIdx.y;            // b*16+h

  const unsigned short* Qg = Qh + ((size_t)bh * 2048 + q0) * 64;

#pragma unroll
  for (int i = 0; i < 2; i++) {
    int kc = w * 2 + i;
    async_cp16(Qg + (size_t)lane * 64 + kc * 8, &Qs[kc * 512]);
  }

  f32x4 Oacc[4];
  float m_[4], l_[4];
#pragma unroll
  for (int t = 0; t < 4; t++) { Oacc[t] = (f32x4)0.0f; }
#pragma unroll
  for (int r = 0; r < 4; r++) { m_[r] = -__builtin_inff(); l_[r] = 0.0f; }

  for (int c = 0; c < 5; c++) {
    const int sc = q0 - 256 + c * 64;   // block-uniform
    if (sc < 0) continue;
    __syncthreads();                    // prior chunk's Ks/Vs reads complete
    const unsigned short* Kg = Kh + ((size_t)bh * 2048 + sc) * 64;
    const unsigned short* Vg = Vt + ((size_t)(bh * 32) + (sc >> 6)) * 4096;
#pragma unroll
    for (int i = 0; i < 2; i++) {
      int kc = w * 2 + i;
      async_cp16(Kg + (size_t)lane * 64 + kc * 8, &Ks[kc * 512]);
      async_cp16(Vg + (size_t)lane * 64 + kc * 8, &Vs[kc * 512]);
    }
    __syncthreads();                    // drains vmcnt -> staging visible

    // ---- S = Q K^T
    f32x4 S[4];
#pragma unroll
    for (int tn = 0; tn < 4; tn++) S[tn] = (f32x4)0.0f;
#pragma unroll
    for (int ks = 0; ks < 2; ks++) {
      int kc = ks * 4 + quad;
      bf16x8 aq = *(const bf16x8*)&Qs[kc * 512 + (w * 16 + l15) * 8];
#pragma unroll
      for (int tn = 0; tn < 4; tn++) {
        bf16x8 bk = *(const bf16x8*)&Ks[kc * 512 + (tn * 16 + l15) * 8];
        S[tn] = __builtin_amdgcn_mfma_f32_16x16x32_bf16(aq, bk, S[tn], 0, 0, 0);
      }
    }

    // ---- mask (only first/last chunk partial)
    const int qb = q0 + w * 16 + quad * 4;  // + r
    if (c == 0) {
#pragma unroll
      for (int tn = 0; tn < 4; tn++) {
        int j = sc + tn * 16 + l15;
#pragma unroll
        for (int r = 0; r < 4; r++)
          if (qb + r > j + (WW - 1)) S[tn][r] = -__builtin_inff();
      }
    } else if (sc == q0) {
#pragma unroll
      for (int tn = 0; tn < 4; tn++) {
        int j = sc + tn * 16 + l15;
#pragma unroll
        for (int r = 0; r < 4; r++)
          if (j > qb + r) S[tn][r] = -__builtin_inff();
      }
    }

    // ---- online softmax
    float mx[4], al[4], em[4], ps[4];
#pragma unroll
    for (int r = 0; r < 4; r++)
      mx[r] = fmaxf(fmaxf(S[0][r], S[1][r]), fmaxf(S[2][r], S[3][r]));
#pragma unroll
    for (int off = 1; off < 16; off <<= 1)
#pragma unroll
      for (int r = 0; r < 4; r++) mx[r] = fmaxf(mx[r], __shfl_xor(mx[r], off));
#pragma unroll
    for (int r = 0; r < 4; r++) {
      float mn = fmaxf(m_[r], mx[r]);
      em[r] = (mn == -__builtin_inff()) ? 0.0f : mn;
      al[r] = __expf(m_[r] - em[r]);
      m_[r] = mn;
    }
#pragma unroll
    for (int tn = 0; tn < 4; tn++)
#pragma unroll
      for (int r = 0; r < 4; r++)
        S[tn][r] = __expf(S[tn][r] - em[r]);
#pragma unroll
    for (int r = 0; r < 4; r++)
      ps[r] = (S[0][r] + S[1][r]) + (S[2][r] + S[3][r]);
#pragma unroll
    for (int off = 1; off < 16; off <<= 1)
#pragma unroll
      for (int r = 0; r < 4; r++) ps[r] += __shfl_xor(ps[r], off);
#pragma unroll
    for (int r = 0; r < 4; r++) l_[r] = l_[r] * al[r] + ps[r];

#pragma unroll
    for (int td = 0; td < 4; td++)
#pragma unroll
      for (int r = 0; r < 4; r++) Oacc[td][r] *= al[r];

    // ---- P -> LDS (bf16)
#pragma unroll
    for (int tn = 0; tn < 4; tn++)
#pragma unroll
      for (int r = 0; r < 4; r++)
        Ps[(w * 16 + quad * 4 + r) * 68 + tn * 16 + l15] = f2bf(S[tn][r]);
    asm volatile("s_waitcnt lgkmcnt(0)" ::: "memory");

    // ---- O += P V
#pragma unroll
    for (int ks = 0; ks < 2; ks++) {
      int off = (w * 16 + l15) * 68 + ks * 32 + quad * 8;
      bf16x4 plo = *(const bf16x4*)&Ps[off];
      bf16x4 phi = *(const bf16x4*)&Ps[off + 4];
      bf16x8 ap = __builtin_shufflevector(plo, phi, 0, 1, 2, 3, 4, 5, 6, 7);
      int kc = ks * 4 + quad;
#pragma unroll
      for (int td = 0; td < 4; td++) {
        bf16x8 bv = *(const bf16x8*)&Vs[kc * 512 + (td * 16 + l15) * 8];
        Oacc[td] = __builtin_amdgcn_mfma_f32_16x16x32_bf16(ap, bv, Oacc[td], 0, 0, 0);
      }
    }
  }

  // ---- epilogue
  const int b = bh >> 4, h = bh & 15;
  float inv[4];
#pragma unroll
  for (int r = 0; r < 4; r++) inv[r] = 1.0f / l_[r];
#pragma unroll
  for (int td = 0; td < 4; td++)
#pragma unroll
    for (int r = 0; r < 4; r++) {
      int q = q0 + w * 16 + quad * 4 + r;
      y[((size_t)(b * 2048 + q)) * 1024 + h * 64 + td * 16 + l15] =
          __float2bfloat16(Oacc[td][r] * inv[r]);
    }
}

// ---------------------------------------------------------------------------
extern "C" void kernel_launch(void* const* d_in, const int* in_sizes, int n_in,
                              void* d_out, int out_size, void* d_ws, size_t ws_size,
                              hipStream_t stream) {
  const float* x     = (const float*)d_in[0];
  const float* wqkv  = (const float*)d_in[1];
  const float* wproj = (const float*)d_in[2];
  float* out = (float*)d_out;

  char* ws = (char*)d_ws;
  // [0,16M)   Apk (packed x; dead after QKV gemm) -> reused as Vt
  // [16,22M)  Wqkv bf16   [22,24M) Wproj bf16  (contiguous for convert_w)
  // [24,40M)  Qh   [40,56M) Kh   [56,72M) Vh   [72,88M) y bf16
  unsigned short* apk    = (unsigned short*)(ws);
  unsigned short* vtb    = (unsigned short*)(ws);  // aliases Apk (after gemm)
  unsigned short* wqkvb  = (unsigned short*)(ws + (size_t)16 * 1024 * 1024);
  unsigned short* wprojb = (unsigned short*)(ws + (size_t)22 * 1024 * 1024);
  unsigned short* qh     = (unsigned short*)(ws + (size_t)24 * 1024 * 1024);
  unsigned short* kh     = (unsigned short*)(ws + (size_t)40 * 1024 * 1024);
  unsigned short* vh     = (unsigned short*)(ws + (size_t)56 * 1024 * 1024);
  unsigned short* yb     = (unsigned short*)(ws + (size_t)72 * 1024 * 1024);

  convert_w<<<(NQ + NP) / 1024, 256, 0, stream>>>(
      wqkv, wproj, (__hip_bfloat16*)wqkvb);
  pack_x<<<dim3(128, 16), 256, 0, stream>>>(x, apk);

  // qkv = x @ Wqkv^T, scattered to head-major Q/K/V (Q pre-scaled)
  gemm_qkv<<<768, 512, 0, stream>>>(apk, wqkvb, qh, kh, vh);

  // V -> chunk-blocked transpose (into Apk region, now dead)
  transpose_v<<<dim3(32, 64), 256, 0, stream>>>(vh, vtb);

  // attention
  attn_mfma<<<dim3(TT / 64, BB * HH), 256, 0, stream>>>(
      qh, kh, vtb, (__hip_bfloat16*)yb);

  // out = y @ Wproj^T -> fp32
  gemm_proj<<<dim3(MM / 128, CC / 128), 256, 0, stream>>>(
      yb, wprojb, out);
}

// Round 8
// 249.000 us; speedup vs baseline: 1.4275x; 1.0202x over previous
//
#include <hip/hip_runtime.h>
#include <hip/hip_bf16.h>
#include <math.h>

// Problem constants
#define BB 4
#define TT 2048
#define CC 1024
#define HH 16
#define DD 64
#define WW 256
#define MM (BB*TT)   // 8192 rows
#define NX (MM*CC)
#define NQ (3*CC*CC)
#define NP (CC*CC)

typedef __bf16 bf16x8 __attribute__((ext_vector_type(8)));
typedef __bf16 bf16x4 __attribute__((ext_vector_type(4)));
typedef float  f32x4  __attribute__((ext_vector_type(4)));

// async global->LDS 16B: LDS dest is wave-uniform base; HW adds lane*16
__device__ __forceinline__ void async_cp16(const void* g, void* l) {
  __builtin_amdgcn_global_load_lds(
      (const __attribute__((address_space(1))) void*)g,
      (__attribute__((address_space(3))) void*)l, 16, 0, 0);
}

__device__ __forceinline__ unsigned short f2bf(float v) {
  __hip_bfloat16 h = __float2bfloat16(v);
  return *(unsigned short*)&h;
}

// ---------------------------------------------------------------------------
// prep: fused (a) weight fp32->bf16 convert, (b) x convert+pack into
// MFMA A-fragment-major layout Apk[((rt*32+g)*64+lane)*8]:
//   rt = row/16, g = k/32, l15 = row%16, quad = (k%32)/8.
// A wave's A-frag load is then ONE coalesced 1KB global_load_dwordx4.
// ---------------------------------------------------------------------------
__global__ __launch_bounds__(256)
void prep(const float* __restrict__ x,
          const float* __restrict__ wq,
          const float* __restrict__ wp,
          __hip_bfloat16* __restrict__ wdst,
          unsigned short* __restrict__ Apk) {
  const int p = blockIdx.x;
  const int tid = threadIdx.x;
  if (p < 4096) {                       // ---- weight convert
    int i = (p * 256 + tid) * 4;
    const float* src; int off;
    if (i < NQ) { src = wq; off = i; }
    else        { src = wp; off = i - NQ; }
    float4 v = *(const float4*)(src + off);
    wdst[i + 0] = __float2bfloat16(v.x);
    wdst[i + 1] = __float2bfloat16(v.y);
    wdst[i + 2] = __float2bfloat16(v.z);
    wdst[i + 3] = __float2bfloat16(v.w);
    return;
  }
  // ---- x convert + pack (64 rows x 64 k per block)
  __shared__ __align__(16) unsigned short tile[64 * 72]; // stride 144B
  const int pid = p - 4096;
  const int bm = pid & 127;    // 0..127
  const int bk = pid >> 7;     // 0..15
  const int tr = tid >> 4;          // 0..15
  const int tc = (tid & 15) * 4;    // 0..60
#pragma unroll
  for (int i = 0; i < 4; i++) {
    int row = i * 16 + tr;
    float4 v = *(const float4*)&x[(size_t)(bm * 64 + row) * 1024 + bk * 64 + tc];
    tile[row * 72 + tc + 0] = f2bf(v.x);
    tile[row * 72 + tc + 1] = f2bf(v.y);
    tile[row * 72 + tc + 2] = f2bf(v.z);
    tile[row * 72 + tc + 3] = f2bf(v.w);
  }
  __syncthreads();
  const int w = tid >> 6, lane = tid & 63;
  const int quad = lane >> 4, l15 = lane & 15;
#pragma unroll
  for (int f = 0; f < 2; f++) {
    bf16x8 fr = *(const bf16x8*)&tile[(w * 16 + l15) * 72 + f * 32 + quad * 8];
    *(bf16x8*)&Apk[(((size_t)(bm * 4 + w) * 32) + bk * 2 + f) * 512 + lane * 8] = fr;
  }
}

// ---------------------------------------------------------------------------
// QKV GEMM (r7-validated): A direct packed-global->VGPR (depth-2 prefetch),
// B LDS double-buffer BK=128, one barrier/stage, XCD swizzle mblk-major.
// __launch_bounds__(512,2) -> 256 regs/wave, no spill (r6's lesson).
// ---------------------------------------------------------------------------
__global__ __launch_bounds__(512, 2)
void gemm_qkv(const unsigned short* __restrict__ Apk,
              const unsigned short* __restrict__ Bw,
              unsigned short* __restrict__ Qh,
              unsigned short* __restrict__ Kh,
              unsigned short* __restrict__ Vh) {
  __shared__ __align__(16) unsigned short Bs0[16 * 1024]; // 32 KB [kc16][col128][8]
  __shared__ __align__(16) unsigned short Bs1[16 * 1024];

  const int id   = blockIdx.x;
  const int xcd  = id & 7;
  const int slot = id >> 3;        // 0..95
  const int mblk = slot / 3;       // 0..31
  const int nloc = slot % 3;       // 0..2
  const int n0 = (xcd * 3 + nloc) * 128;
  const int m0 = mblk * 256;

  const int tid  = threadIdx.x;
  const int w    = tid >> 6;       // 0..7
  const int lane = tid & 63;
  const int quad = lane >> 4;
  const int l15  = lane & 15;
  const int wm = w & 3;
  const int wn = w >> 2;

  f32x4 acc[4][4];
#pragma unroll
  for (int i = 0; i < 4; i++)
#pragma unroll
    for (int j = 0; j < 4; j++) acc[i][j] = (f32x4)0.0f;

  const unsigned short* abase =
      Apk + ((size_t)((m0 >> 4) + wm * 4) * 32) * 512 + lane * 8;

  auto stageB = [&](int k0, unsigned short* bs) {
#pragma unroll
    for (int i = 0; i < 4; i++) {
      int idx  = w + 8 * i;
      int kc   = idx >> 1;
      int half = idx & 1;
      async_cp16(Bw + (size_t)(n0 + half * 64 + lane) * 1024 + k0 + kc * 8,
                 &bs[kc * 1024 + half * 512]);
    }
  };

  bf16x8 Af[3][4];
  auto loadA = [&](int g, bf16x8* fr) {
#pragma unroll
    for (int tm = 0; tm < 4; tm++)
      fr[tm] = *(const bf16x8*)(abase + ((size_t)(tm * 32 + g)) * 512);
  };

  loadA(0, Af[0]);
  loadA(1, Af[1]);
  stageB(0, Bs0);
  __syncthreads();

#pragma unroll
  for (int s = 0; s < 8; s++) {
    const unsigned short* bs = (s & 1) ? Bs1 : Bs0;
    if (s + 1 < 8) stageB((s + 1) * 128, (s & 1) ? Bs0 : Bs1);
#pragma unroll
    for (int sub = 0; sub < 4; sub++) {
      const int g = s * 4 + sub;
      if (g + 2 < 32) loadA(g + 2, Af[(g + 2) % 3]);
      const bf16x8* af = Af[g % 3];
      bf16x8 bfv[4];
#pragma unroll
      for (int tn = 0; tn < 4; tn++)
        bfv[tn] = *(const bf16x8*)
            &bs[(sub * 4 + quad) * 1024 + (wn * 64 + tn * 16 + l15) * 8];
#pragma unroll
      for (int tm = 0; tm < 4; tm++)
#pragma unroll
        for (int tn = 0; tn < 4; tn++)
          acc[tm][tn] = __builtin_amdgcn_mfma_f32_16x16x32_bf16(
              af[tm], bfv[tn], acc[tm][tn], 0, 0, 0);
    }
    __syncthreads();
  }

  // scatter qkv: col -> (which, head, d); row -> (b, t)
#pragma unroll
  for (int tm = 0; tm < 4; tm++)
#pragma unroll
    for (int tn = 0; tn < 4; tn++) {
      int colb = n0 + wn * 64 + tn * 16;
      int t3 = colb >> 10;
      int hh = (colb >> 6) & 15;
      int dd = (colb & 63) + l15;
      unsigned short* dst = (t3 == 0) ? Qh : ((t3 == 1) ? Kh : Vh);
      float sc = (t3 == 0) ? 0.125f : 1.0f;
#pragma unroll
      for (int r = 0; r < 4; r++) {
        int row = m0 + wm * 64 + tm * 16 + quad * 4 + r;
        int b = row >> 11, tt = row & 2047;
        dst[((size_t)((b * 16 + hh) * 2048 + tt)) * 64 + dd] =
            f2bf(acc[tm][tn][r] * sc);
      }
    }
}

// ---------------------------------------------------------------------------
// Proj GEMM (round 8): r7 structure. A = packed y-frags (written by attn
// epilogue), B = Wproj in LDS dbuf. 256 blocks: xcd=id&7 owns n-panel
// n0=xcd*128; m0=(id>>3)*256. fp32 output row-major.
// ---------------------------------------------------------------------------
__global__ __launch_bounds__(512, 2)
void gemm_proj(const unsigned short* __restrict__ Apk,
               const unsigned short* __restrict__ Bw,
               float* __restrict__ Co) {
  __shared__ __align__(16) unsigned short Bs0[16 * 1024];
  __shared__ __align__(16) unsigned short Bs1[16 * 1024];

  const int id = blockIdx.x;
  const int n0 = (id & 7) * 128;
  const int m0 = (id >> 3) * 256;

  const int tid  = threadIdx.x;
  const int w    = tid >> 6;
  const int lane = tid & 63;
  const int quad = lane >> 4;
  const int l15  = lane & 15;
  const int wm = w & 3;
  const int wn = w >> 2;

  f32x4 acc[4][4];
#pragma unroll
  for (int i = 0; i < 4; i++)
#pragma unroll
    for (int j = 0; j < 4; j++) acc[i][j] = (f32x4)0.0f;

  const unsigned short* abase =
      Apk + ((size_t)((m0 >> 4) + wm * 4) * 32) * 512 + lane * 8;

  auto stageB = [&](int k0, unsigned short* bs) {
#pragma unroll
    for (int i = 0; i < 4; i++) {
      int idx  = w + 8 * i;
      int kc   = idx >> 1;
      int half = idx & 1;
      async_cp16(Bw + (size_t)(n0 + half * 64 + lane) * 1024 + k0 + kc * 8,
                 &bs[kc * 1024 + half * 512]);
    }
  };

  bf16x8 Af[3][4];
  auto loadA = [&](int g, bf16x8* fr) {
#pragma unroll
    for (int tm = 0; tm < 4; tm++)
      fr[tm] = *(const bf16x8*)(abase + ((size_t)(tm * 32 + g)) * 512);
  };

  loadA(0, Af[0]);
  loadA(1, Af[1]);
  stageB(0, Bs0);
  __syncthreads();

#pragma unroll
  for (int s = 0; s < 8; s++) {
    const unsigned short* bs = (s & 1) ? Bs1 : Bs0;
    if (s + 1 < 8) stageB((s + 1) * 128, (s & 1) ? Bs0 : Bs1);
#pragma unroll
    for (int sub = 0; sub < 4; sub++) {
      const int g = s * 4 + sub;
      if (g + 2 < 32) loadA(g + 2, Af[(g + 2) % 3]);
      const bf16x8* af = Af[g % 3];
      bf16x8 bfv[4];
#pragma unroll
      for (int tn = 0; tn < 4; tn++)
        bfv[tn] = *(const bf16x8*)
            &bs[(sub * 4 + quad) * 1024 + (wn * 64 + tn * 16 + l15) * 8];
#pragma unroll
      for (int tm = 0; tm < 4; tm++)
#pragma unroll
        for (int tn = 0; tn < 4; tn++)
          acc[tm][tn] = __builtin_amdgcn_mfma_f32_16x16x32_bf16(
              af[tm], bfv[tn], acc[tm][tn], 0, 0, 0);
    }
    __syncthreads();
  }

#pragma unroll
  for (int tm = 0; tm < 4; tm++)
#pragma unroll
    for (int tn = 0; tn < 4; tn++)
#pragma unroll
      for (int r = 0; r < 4; r++) {
        int row = m0 + wm * 64 + tm * 16 + quad * 4 + r;
        int col = n0 + wn * 64 + tn * 16 + l15;
        Co[(size_t)row * 1024 + col] = acc[tm][tn][r];
      }
}

// ---------------------------------------------------------------------------
// Vh [bh][t][d] -> Vt chunk-blocked [bh][tc=32][d=64][tin=64]
// ---------------------------------------------------------------------------
__global__ __launch_bounds__(256)
void transpose_v(const unsigned short* __restrict__ Vh,
                 unsigned short* __restrict__ Vt) {
  __shared__ __align__(16) unsigned short tile[64 * 72];
  const int tid = threadIdx.x;
  const int tc = blockIdx.x, bh = blockIdx.y;
  const unsigned short* src = Vh + ((size_t)bh * 2048 + (size_t)tc * 64) * 64;
  for (int i = tid; i < 512; i += 256) {
    int r = i >> 3, ds = (i & 7) * 8;
    *(uint4*)&tile[r * 72 + ds] = *(const uint4*)&src[(size_t)r * 64 + ds];
  }
  __syncthreads();
  unsigned short* dst = Vt + (size_t)(bh * 32 + tc) * 4096;
  for (int i = tid; i < 512; i += 256) {
    int d = i >> 3, ts = (i & 7) * 8;
    unsigned int w0 = tile[(ts + 0) * 72 + d] | ((unsigned int)tile[(ts + 1) * 72 + d] << 16);
    unsigned int w1 = tile[(ts + 2) * 72 + d] | ((unsigned int)tile[(ts + 3) * 72 + d] << 16);
    unsigned int w2 = tile[(ts + 4) * 72 + d] | ((unsigned int)tile[(ts + 5) * 72 + d] << 16);
    unsigned int w3 = tile[(ts + 6) * 72 + d] | ((unsigned int)tile[(ts + 7) * 72 + d] << 16);
    uint4 o; o.x = w0; o.y = w1; o.z = w2; o.w = w3;
    *(uint4*)&dst[(size_t)d * 64 + ts] = o;
  }
}

// ---------------------------------------------------------------------------
// MFMA sliding-window flash attention. NEW (round 8): epilogue writes y
// directly in proj's A-fragment-packed layout via a per-wave LDS transpose
// (within-wave data only -> lgkmcnt wait, no barrier).
// ---------------------------------------------------------------------------
__global__ __launch_bounds__(256, 2)
void attn_mfma(const unsigned short* __restrict__ Qh,
               const unsigned short* __restrict__ Kh,
               const unsigned short* __restrict__ Vt,
               unsigned short* __restrict__ Ypk) {
  __shared__ __align__(16) unsigned short Qs[8 * 512];
  __shared__ __align__(16) unsigned short Ks[8 * 512];
  __shared__ __align__(16) unsigned short Vs[8 * 512];
  __shared__ __align__(16) unsigned short Ps[64 * 68];
  __shared__ __align__(16) unsigned short Ot[64 * 72]; // epilogue transpose

  const int tid  = threadIdx.x;
  const int w    = tid >> 6;
  const int lane = tid & 63;
  const int quad = lane >> 4;
  const int l15  = lane & 15;
  const int q0 = blockIdx.x * 64;
  const int bh = blockIdx.y;            // b*16+h

  const unsigned short* Qg = Qh + ((size_t)bh * 2048 + q0) * 64;

#pragma unroll
  for (int i = 0; i < 2; i++) {
    int kc = w * 2 + i;
    async_cp16(Qg + (size_t)lane * 64 + kc * 8, &Qs[kc * 512]);
  }

  f32x4 Oacc[4];
  float m_[4], l_[4];
#pragma unroll
  for (int t = 0; t < 4; t++) { Oacc[t] = (f32x4)0.0f; }
#pragma unroll
  for (int r = 0; r < 4; r++) { m_[r] = -__builtin_inff(); l_[r] = 0.0f; }

  for (int c = 0; c < 5; c++) {
    const int sc = q0 - 256 + c * 64;
    if (sc < 0) continue;
    __syncthreads();
    const unsigned short* Kg = Kh + ((size_t)bh * 2048 + sc) * 64;
    const unsigned short* Vg = Vt + ((size_t)(bh * 32) + (sc >> 6)) * 4096;
#pragma unroll
    for (int i = 0; i < 2; i++) {
      int kc = w * 2 + i;
      async_cp16(Kg + (size_t)lane * 64 + kc * 8, &Ks[kc * 512]);
      async_cp16(Vg + (size_t)lane * 64 + kc * 8, &Vs[kc * 512]);
    }
    __syncthreads();

    // ---- S = Q K^T
    f32x4 S[4];
#pragma unroll
    for (int tn = 0; tn < 4; tn++) S[tn] = (f32x4)0.0f;
#pragma unroll
    for (int ks = 0; ks < 2; ks++) {
      int kc = ks * 4 + quad;
      bf16x8 aq = *(const bf16x8*)&Qs[kc * 512 + (w * 16 + l15) * 8];
#pragma unroll
      for (int tn = 0; tn < 4; tn++) {
        bf16x8 bk = *(const bf16x8*)&Ks[kc * 512 + (tn * 16 + l15) * 8];
        S[tn] = __builtin_amdgcn_mfma_f32_16x16x32_bf16(aq, bk, S[tn], 0, 0, 0);
      }
    }

    // ---- mask (only first/last chunk partial)
    const int qb = q0 + w * 16 + quad * 4;
    if (c == 0) {
#pragma unroll
      for (int tn = 0; tn < 4; tn++) {
        int j = sc + tn * 16 + l15;
#pragma unroll
        for (int r = 0; r < 4; r++)
          if (qb + r > j + (WW - 1)) S[tn][r] = -__builtin_inff();
      }
    } else if (sc == q0) {
#pragma unroll
      for (int tn = 0; tn < 4; tn++) {
        int j = sc + tn * 16 + l15;
#pragma unroll
        for (int r = 0; r < 4; r++)
          if (j > qb + r) S[tn][r] = -__builtin_inff();
      }
    }

    // ---- online softmax
    float mx[4], al[4], em[4], ps[4];
#pragma unroll
    for (int r = 0; r < 4; r++)
      mx[r] = fmaxf(fmaxf(S[0][r], S[1][r]), fmaxf(S[2][r], S[3][r]));
#pragma unroll
    for (int off = 1; off < 16; off <<= 1)
#pragma unroll
      for (int r = 0; r < 4; r++) mx[r] = fmaxf(mx[r], __shfl_xor(mx[r], off));
#pragma unroll
    for (int r = 0; r < 4; r++) {
      float mn = fmaxf(m_[r], mx[r]);
      em[r] = (mn == -__builtin_inff()) ? 0.0f : mn;
      al[r] = __expf(m_[r] - em[r]);
      m_[r] = mn;
    }
#pragma unroll
    for (int tn = 0; tn < 4; tn++)
#pragma unroll
      for (int r = 0; r < 4; r++)
        S[tn][r] = __expf(S[tn][r] - em[r]);
#pragma unroll
    for (int r = 0; r < 4; r++)
      ps[r] = (S[0][r] + S[1][r]) + (S[2][r] + S[3][r]);
#pragma unroll
    for (int off = 1; off < 16; off <<= 1)
#pragma unroll
      for (int r = 0; r < 4; r++) ps[r] += __shfl_xor(ps[r], off);
#pragma unroll
    for (int r = 0; r < 4; r++) l_[r] = l_[r] * al[r] + ps[r];

#pragma unroll
    for (int td = 0; td < 4; td++)
#pragma unroll
      for (int r = 0; r < 4; r++) Oacc[td][r] *= al[r];

    // ---- P -> LDS (bf16)
#pragma unroll
    for (int tn = 0; tn < 4; tn++)
#pragma unroll
      for (int r = 0; r < 4; r++)
        Ps[(w * 16 + quad * 4 + r) * 68 + tn * 16 + l15] = f2bf(S[tn][r]);
    asm volatile("s_waitcnt lgkmcnt(0)" ::: "memory");

    // ---- O += P V
#pragma unroll
    for (int ks = 0; ks < 2; ks++) {
      int off = (w * 16 + l15) * 68 + ks * 32 + quad * 8;
      bf16x4 plo = *(const bf16x4*)&Ps[off];
      bf16x4 phi = *(const bf16x4*)&Ps[off + 4];
      bf16x8 ap = __builtin_shufflevector(plo, phi, 0, 1, 2, 3, 4, 5, 6, 7);
      int kc = ks * 4 + quad;
#pragma unroll
      for (int td = 0; td < 4; td++) {
        bf16x8 bv = *(const bf16x8*)&Vs[kc * 512 + (td * 16 + l15) * 8];
        Oacc[td] = __builtin_amdgcn_mfma_f32_16x16x32_bf16(ap, bv, Oacc[td], 0, 0, 0);
      }
    }
  }

  // ---- epilogue: write y in proj's A-frag-packed layout.
  // Row block rt = (b*2048 + q0)/16 + w; k-chunks g = h*2 + f.
  // Per-wave LDS transpose: wave w writes rows w*16.., reads only its own.
  const int b = bh >> 4, h = bh & 15;
  float inv[4];
#pragma unroll
  for (int r = 0; r < 4; r++) inv[r] = 1.0f / l_[r];
#pragma unroll
  for (int td = 0; td < 4; td++)
#pragma unroll
    for (int r = 0; r < 4; r++)
      Ot[(w * 16 + quad * 4 + r) * 72 + td * 16 + l15] =
          f2bf(Oacc[td][r] * inv[r]);
  asm volatile("s_waitcnt lgkmcnt(0)" ::: "memory");
  const size_t rt = (size_t)((b * 2048 + q0) >> 4) + w;
#pragma unroll
  for (int f = 0; f < 2; f++) {
    bf16x8 fr = *(const bf16x8*)&Ot[(w * 16 + l15) * 72 + f * 32 + quad * 8];
    *(bf16x8*)&Ypk[(rt * 32 + h * 2 + f) * 512 + lane * 8] = fr;
  }
}

// ---------------------------------------------------------------------------
extern "C" void kernel_launch(void* const* d_in, const int* in_sizes, int n_in,
                              void* d_out, int out_size, void* d_ws, size_t ws_size,
                              hipStream_t stream) {
  const float* x     = (const float*)d_in[0];
  const float* wqkv  = (const float*)d_in[1];
  const float* wproj = (const float*)d_in[2];
  float* out = (float*)d_out;

  char* ws = (char*)d_ws;
  // [0,16M)   Apk (packed x; dead after QKV gemm) -> reused as Vt
  // [16,22M)  Wqkv bf16   [22,24M) Wproj bf16  (contiguous for prep)
  // [24,40M)  Qh   [40,56M) Kh   [56,72M) Vh   [72,88M) Ypk (packed y)
  unsigned short* apk    = (unsigned short*)(ws);
  unsigned short* vtb    = (unsigned short*)(ws);  // aliases Apk (after gemm)
  unsigned short* wqkvb  = (unsigned short*)(ws + (size_t)16 * 1024 * 1024);
  unsigned short* wprojb = (unsigned short*)(ws + (size_t)22 * 1024 * 1024);
  unsigned short* qh     = (unsigned short*)(ws + (size_t)24 * 1024 * 1024);
  unsigned short* kh     = (unsigned short*)(ws + (size_t)40 * 1024 * 1024);
  unsigned short* vh     = (unsigned short*)(ws + (size_t)56 * 1024 * 1024);
  unsigned short* ypk    = (unsigned short*)(ws + (size_t)72 * 1024 * 1024);

  // fused convert(W) + convert/pack(x)
  prep<<<4096 + 2048, 256, 0, stream>>>(
      x, wqkv, wproj, (__hip_bfloat16*)wqkvb, apk);

  // qkv = x @ Wqkv^T, scattered to head-major Q/K/V (Q pre-scaled)
  gemm_qkv<<<768, 512, 0, stream>>>(apk, wqkvb, qh, kh, vh);

  // V -> chunk-blocked transpose (into Apk region, now dead)
  transpose_v<<<dim3(32, 64), 256, 0, stream>>>(vh, vtb);

  // attention -> packed y
  attn_mfma<<<dim3(TT / 64, BB * HH), 256, 0, stream>>>(
      qh, kh, vtb, ypk);

  // out = y @ Wproj^T -> fp32
  gemm_proj<<<256, 512, 0, stream>>>(ypk, wprojb, out);
}

// Round 9
// 245.310 us; speedup vs baseline: 1.4490x; 1.0150x over previous
//
#include <hip/hip_runtime.h>
#include <hip/hip_bf16.h>
#include <math.h>

// Problem constants
#define BB 4
#define TT 2048
#define CC 1024
#define HH 16
#define DD 64
#define WW 256
#define MM (BB*TT)   // 8192 rows
#define NX (MM*CC)
#define NQ (3*CC*CC)
#define NP (CC*CC)

typedef __bf16 bf16x8 __attribute__((ext_vector_type(8)));
typedef __bf16 bf16x4 __attribute__((ext_vector_type(4)));
typedef float  f32x4  __attribute__((ext_vector_type(4)));

// async global->LDS 16B: LDS dest is wave-uniform base; HW adds lane*16
__device__ __forceinline__ void async_cp16(const void* g, void* l) {
  __builtin_amdgcn_global_load_lds(
      (const __attribute__((address_space(1))) void*)g,
      (__attribute__((address_space(3))) void*)l, 16, 0, 0);
}

__device__ __forceinline__ unsigned short f2bf(float v) {
  __hip_bfloat16 h = __float2bfloat16(v);
  return *(unsigned short*)&h;
}

// ---------------------------------------------------------------------------
// prep: fused (a) weight fp32->bf16 convert, (b) x convert+pack into
// MFMA A-fragment-major layout Apk[((rt*32+g)*64+lane)*8].
// ---------------------------------------------------------------------------
__global__ __launch_bounds__(256)
void prep(const float* __restrict__ x,
          const float* __restrict__ wq,
          const float* __restrict__ wp,
          __hip_bfloat16* __restrict__ wdst,
          unsigned short* __restrict__ Apk) {
  const int p = blockIdx.x;
  const int tid = threadIdx.x;
  if (p < 4096) {                       // ---- weight convert
    int i = (p * 256 + tid) * 4;
    const float* src; int off;
    if (i < NQ) { src = wq; off = i; }
    else        { src = wp; off = i - NQ; }
    float4 v = *(const float4*)(src + off);
    wdst[i + 0] = __float2bfloat16(v.x);
    wdst[i + 1] = __float2bfloat16(v.y);
    wdst[i + 2] = __float2bfloat16(v.z);
    wdst[i + 3] = __float2bfloat16(v.w);
    return;
  }
  // ---- x convert + pack (64 rows x 64 k per block)
  __shared__ __align__(16) unsigned short tile[64 * 72]; // stride 144B
  const int pid = p - 4096;
  const int bm = pid & 127;    // 0..127
  const int bk = pid >> 7;     // 0..15
  const int tr = tid >> 4;          // 0..15
  const int tc = (tid & 15) * 4;    // 0..60
#pragma unroll
  for (int i = 0; i < 4; i++) {
    int row = i * 16 + tr;
    float4 v = *(const float4*)&x[(size_t)(bm * 64 + row) * 1024 + bk * 64 + tc];
    tile[row * 72 + tc + 0] = f2bf(v.x);
    tile[row * 72 + tc + 1] = f2bf(v.y);
    tile[row * 72 + tc + 2] = f2bf(v.z);
    tile[row * 72 + tc + 3] = f2bf(v.w);
  }
  __syncthreads();
  const int w = tid >> 6, lane = tid & 63;
  const int quad = lane >> 4, l15 = lane & 15;
#pragma unroll
  for (int f = 0; f < 2; f++) {
    bf16x8 fr = *(const bf16x8*)&tile[(w * 16 + l15) * 72 + f * 32 + quad * 8];
    *(bf16x8*)&Apk[(((size_t)(bm * 4 + w) * 32) + bk * 2 + f) * 512 + lane * 8] = fr;
  }
}

// ---------------------------------------------------------------------------
// QKV GEMM (r7-validated): A direct packed-global->VGPR (depth-2 prefetch),
// B LDS double-buffer BK=128, one barrier/stage, XCD swizzle mblk-major.
// ---------------------------------------------------------------------------
__global__ __launch_bounds__(512, 2)
void gemm_qkv(const unsigned short* __restrict__ Apk,
              const unsigned short* __restrict__ Bw,
              unsigned short* __restrict__ Qh,
              unsigned short* __restrict__ Kh,
              unsigned short* __restrict__ Vh) {
  __shared__ __align__(16) unsigned short Bs0[16 * 1024]; // 32 KB
  __shared__ __align__(16) unsigned short Bs1[16 * 1024];

  const int id   = blockIdx.x;
  const int xcd  = id & 7;
  const int slot = id >> 3;
  const int mblk = slot / 3;
  const int nloc = slot % 3;
  const int n0 = (xcd * 3 + nloc) * 128;
  const int m0 = mblk * 256;

  const int tid  = threadIdx.x;
  const int w    = tid >> 6;
  const int lane = tid & 63;
  const int quad = lane >> 4;
  const int l15  = lane & 15;
  const int wm = w & 3;
  const int wn = w >> 2;

  f32x4 acc[4][4];
#pragma unroll
  for (int i = 0; i < 4; i++)
#pragma unroll
    for (int j = 0; j < 4; j++) acc[i][j] = (f32x4)0.0f;

  const unsigned short* abase =
      Apk + ((size_t)((m0 >> 4) + wm * 4) * 32) * 512 + lane * 8;

  auto stageB = [&](int k0, unsigned short* bs) {
#pragma unroll
    for (int i = 0; i < 4; i++) {
      int idx  = w + 8 * i;
      int kc   = idx >> 1;
      int half = idx & 1;
      async_cp16(Bw + (size_t)(n0 + half * 64 + lane) * 1024 + k0 + kc * 8,
                 &bs[kc * 1024 + half * 512]);
    }
  };

  bf16x8 Af[3][4];
  auto loadA = [&](int g, bf16x8* fr) {
#pragma unroll
    for (int tm = 0; tm < 4; tm++)
      fr[tm] = *(const bf16x8*)(abase + ((size_t)(tm * 32 + g)) * 512);
  };

  loadA(0, Af[0]);
  loadA(1, Af[1]);
  stageB(0, Bs0);
  __syncthreads();

#pragma unroll
  for (int s = 0; s < 8; s++) {
    const unsigned short* bs = (s & 1) ? Bs1 : Bs0;
    if (s + 1 < 8) stageB((s + 1) * 128, (s & 1) ? Bs0 : Bs1);
#pragma unroll
    for (int sub = 0; sub < 4; sub++) {
      const int g = s * 4 + sub;
      if (g + 2 < 32) loadA(g + 2, Af[(g + 2) % 3]);
      const bf16x8* af = Af[g % 3];
      bf16x8 bfv[4];
#pragma unroll
      for (int tn = 0; tn < 4; tn++)
        bfv[tn] = *(const bf16x8*)
            &bs[(sub * 4 + quad) * 1024 + (wn * 64 + tn * 16 + l15) * 8];
#pragma unroll
      for (int tm = 0; tm < 4; tm++)
#pragma unroll
        for (int tn = 0; tn < 4; tn++)
          acc[tm][tn] = __builtin_amdgcn_mfma_f32_16x16x32_bf16(
              af[tm], bfv[tn], acc[tm][tn], 0, 0, 0);
    }
    __syncthreads();
  }

  // scatter qkv: col -> (which, head, d); row -> (b, t)
#pragma unroll
  for (int tm = 0; tm < 4; tm++)
#pragma unroll
    for (int tn = 0; tn < 4; tn++) {
      int colb = n0 + wn * 64 + tn * 16;
      int t3 = colb >> 10;
      int hh = (colb >> 6) & 15;
      int dd = (colb & 63) + l15;
      unsigned short* dst = (t3 == 0) ? Qh : ((t3 == 1) ? Kh : Vh);
      float sc = (t3 == 0) ? 0.125f : 1.0f;
#pragma unroll
      for (int r = 0; r < 4; r++) {
        int row = m0 + wm * 64 + tm * 16 + quad * 4 + r;
        int b = row >> 11, tt = row & 2047;
        dst[((size_t)((b * 16 + hh) * 2048 + tt)) * 64 + dd] =
            f2bf(acc[tm][tn][r] * sc);
      }
    }
}

// ---------------------------------------------------------------------------
// Proj GEMM (r8-validated): A = packed y-frags, B = Wproj LDS dbuf.
// ---------------------------------------------------------------------------
__global__ __launch_bounds__(512, 2)
void gemm_proj(const unsigned short* __restrict__ Apk,
               const unsigned short* __restrict__ Bw,
               float* __restrict__ Co) {
  __shared__ __align__(16) unsigned short Bs0[16 * 1024];
  __shared__ __align__(16) unsigned short Bs1[16 * 1024];

  const int id = blockIdx.x;
  const int n0 = (id & 7) * 128;
  const int m0 = (id >> 3) * 256;

  const int tid  = threadIdx.x;
  const int w    = tid >> 6;
  const int lane = tid & 63;
  const int quad = lane >> 4;
  const int l15  = lane & 15;
  const int wm = w & 3;
  const int wn = w >> 2;

  f32x4 acc[4][4];
#pragma unroll
  for (int i = 0; i < 4; i++)
#pragma unroll
    for (int j = 0; j < 4; j++) acc[i][j] = (f32x4)0.0f;

  const unsigned short* abase =
      Apk + ((size_t)((m0 >> 4) + wm * 4) * 32) * 512 + lane * 8;

  auto stageB = [&](int k0, unsigned short* bs) {
#pragma unroll
    for (int i = 0; i < 4; i++) {
      int idx  = w + 8 * i;
      int kc   = idx >> 1;
      int half = idx & 1;
      async_cp16(Bw + (size_t)(n0 + half * 64 + lane) * 1024 + k0 + kc * 8,
                 &bs[kc * 1024 + half * 512]);
    }
  };

  bf16x8 Af[3][4];
  auto loadA = [&](int g, bf16x8* fr) {
#pragma unroll
    for (int tm = 0; tm < 4; tm++)
      fr[tm] = *(const bf16x8*)(abase + ((size_t)(tm * 32 + g)) * 512);
  };

  loadA(0, Af[0]);
  loadA(1, Af[1]);
  stageB(0, Bs0);
  __syncthreads();

#pragma unroll
  for (int s = 0; s < 8; s++) {
    const unsigned short* bs = (s & 1) ? Bs1 : Bs0;
    if (s + 1 < 8) stageB((s + 1) * 128, (s & 1) ? Bs0 : Bs1);
#pragma unroll
    for (int sub = 0; sub < 4; sub++) {
      const int g = s * 4 + sub;
      if (g + 2 < 32) loadA(g + 2, Af[(g + 2) % 3]);
      const bf16x8* af = Af[g % 3];
      bf16x8 bfv[4];
#pragma unroll
      for (int tn = 0; tn < 4; tn++)
        bfv[tn] = *(const bf16x8*)
            &bs[(sub * 4 + quad) * 1024 + (wn * 64 + tn * 16 + l15) * 8];
#pragma unroll
      for (int tm = 0; tm < 4; tm++)
#pragma unroll
        for (int tn = 0; tn < 4; tn++)
          acc[tm][tn] = __builtin_amdgcn_mfma_f32_16x16x32_bf16(
              af[tm], bfv[tn], acc[tm][tn], 0, 0, 0);
    }
    __syncthreads();
  }

#pragma unroll
  for (int tm = 0; tm < 4; tm++)
#pragma unroll
    for (int tn = 0; tn < 4; tn++)
#pragma unroll
      for (int r = 0; r < 4; r++) {
        int row = m0 + wm * 64 + tm * 16 + quad * 4 + r;
        int col = n0 + wn * 64 + tn * 16 + l15;
        Co[(size_t)row * 1024 + col] = acc[tm][tn][r];
      }
}

// ---------------------------------------------------------------------------
// Vh [bh][t][d] -> Vt chunk-blocked [bh][tc=32][d=64][tin=64]
// ---------------------------------------------------------------------------
__global__ __launch_bounds__(256)
void transpose_v(const unsigned short* __restrict__ Vh,
                 unsigned short* __restrict__ Vt) {
  __shared__ __align__(16) unsigned short tile[64 * 72];
  const int tid = threadIdx.x;
  const int tc = blockIdx.x, bh = blockIdx.y;
  const unsigned short* src = Vh + ((size_t)bh * 2048 + (size_t)tc * 64) * 64;
  for (int i = tid; i < 512; i += 256) {
    int r = i >> 3, ds = (i & 7) * 8;
    *(uint4*)&tile[r * 72 + ds] = *(const uint4*)&src[(size_t)r * 64 + ds];
  }
  __syncthreads();
  unsigned short* dst = Vt + (size_t)(bh * 32 + tc) * 4096;
  for (int i = tid; i < 512; i += 256) {
    int d = i >> 3, ts = (i & 7) * 8;
    unsigned int w0 = tile[(ts + 0) * 72 + d] | ((unsigned int)tile[(ts + 1) * 72 + d] << 16);
    unsigned int w1 = tile[(ts + 2) * 72 + d] | ((unsigned int)tile[(ts + 3) * 72 + d] << 16);
    unsigned int w2 = tile[(ts + 4) * 72 + d] | ((unsigned int)tile[(ts + 5) * 72 + d] << 16);
    unsigned int w3 = tile[(ts + 6) * 72 + d] | ((unsigned int)tile[(ts + 7) * 72 + d] << 16);
    uint4 o; o.x = w0; o.y = w1; o.z = w2; o.w = w3;
    *(uint4*)&dst[(size_t)d * 64 + ts] = o;
  }
}

// ---------------------------------------------------------------------------
// MFMA sliding-window flash attention, SINGLE-STAGE (round 9):
//  - Q A-fragments direct global->VGPR (2 x 16B/lane loads).
//  - ALL 5 K-chunks + 5 V-chunks staged in one DMA burst (80 KB LDS),
//    ONE drain barrier (vs 10 barriers/5 drains in r8).
//  - Plain (non-online) softmax once over the full 320-wide row: no
//    per-chunk m/l updates, no O rescaling.
//  - Barrier 2, then Ps (ping-pong, aliases dead K region) + PV MFMAs.
//  - Epilogue writes y in proj's A-frag-packed layout (r8-validated).
// ---------------------------------------------------------------------------
__global__ __launch_bounds__(256, 2)
void attn_mfma(const unsigned short* __restrict__ Qh,
               const unsigned short* __restrict__ Kh,
               const unsigned short* __restrict__ Vt,
               unsigned short* __restrict__ Ypk) {
  // [0,20480) shorts: K chunks (5 x 4096)   [20480,40960): V chunks
  // After barrier 2 (K dead): Ps ping-pong at 0 / 4608, Ot at 10240.
  __shared__ __align__(16) unsigned short SH[40960];   // 80 KB

  const int tid  = threadIdx.x;
  const int w    = tid >> 6;
  const int lane = tid & 63;
  const int quad = lane >> 4;
  const int l15  = lane & 15;
  const int q0 = blockIdx.x * 64;
  const int bh = blockIdx.y;            // b*16+h

  const int c0 = (q0 >= 256) ? 0 : (4 - (q0 >> 6));  // first valid chunk

  // Q A-fragments direct from global (row = w*16+l15, k = fs*32+quad*8)
  const unsigned short* Qg = Qh + ((size_t)bh * 2048 + q0) * 64;
  bf16x8 Qf[2];
#pragma unroll
  for (int fs = 0; fs < 2; fs++)
    Qf[fs] = *(const bf16x8*)(Qg + (w * 16 + l15) * 64 + fs * 32 + quad * 8);

  // stage all valid K/V chunks in one burst
  const unsigned short* Kg = Kh + (size_t)bh * 2048 * 64;
  const unsigned short* Vg = Vt + (size_t)bh * 32 * 4096;
  for (int ch = c0; ch < 5; ch++) {
    int sc = q0 - 256 + ch * 64;
#pragma unroll
    for (int i = 0; i < 2; i++) {
      int kc = w * 2 + i;
      async_cp16(Kg + (size_t)(sc + lane) * 64 + kc * 8,
                 &SH[ch * 4096 + kc * 512]);
      async_cp16(Vg + (size_t)(sc >> 6) * 4096 + lane * 64 + kc * 8,
                 &SH[20480 + ch * 4096 + kc * 512]);
    }
  }
  __syncthreads();                      // ONE drain for everything

  // ---- S = Q K^T, all chunks into registers
  f32x4 S[5][4];
#pragma unroll
  for (int ch = 0; ch < 5; ch++)
#pragma unroll
    for (int tn = 0; tn < 4; tn++) S[ch][tn] = (f32x4)0.0f;

#pragma unroll
  for (int ch = 0; ch < 5; ch++) {
    if (ch < c0) continue;              // block-uniform
#pragma unroll
    for (int ks = 0; ks < 2; ks++) {
      int kc = ks * 4 + quad;
#pragma unroll
      for (int tn = 0; tn < 4; tn++) {
        bf16x8 bk = *(const bf16x8*)
            &SH[ch * 4096 + kc * 512 + (tn * 16 + l15) * 8];
        S[ch][tn] = __builtin_amdgcn_mfma_f32_16x16x32_bf16(
            Qf[ks], bk, S[ch][tn], 0, 0, 0);
      }
    }
  }

  // ---- masks: chunk 0 (far edge, only if c0==0) and chunk 4 (diagonal)
  const int qb = q0 + w * 16 + quad * 4;
  if (c0 == 0) {
#pragma unroll
    for (int tn = 0; tn < 4; tn++) {
      int j = q0 - 256 + tn * 16 + l15;
#pragma unroll
      for (int r = 0; r < 4; r++)
        if (qb + r > j + (WW - 1)) S[0][tn][r] = -__builtin_inff();
    }
  }
#pragma unroll
  for (int tn = 0; tn < 4; tn++) {
    int j = q0 + tn * 16 + l15;
#pragma unroll
    for (int r = 0; r < 4; r++)
      if (j > qb + r) S[4][tn][r] = -__builtin_inff();
  }

  // ---- plain softmax over the full row (every row has >=1 valid col)
  float mrow[4], lrow[4];
#pragma unroll
  for (int r = 0; r < 4; r++) mrow[r] = -__builtin_inff();
#pragma unroll
  for (int ch = 0; ch < 5; ch++) {
    if (ch < c0) continue;
#pragma unroll
    for (int tn = 0; tn < 4; tn++)
#pragma unroll
      for (int r = 0; r < 4; r++)
        mrow[r] = fmaxf(mrow[r], S[ch][tn][r]);
  }
#pragma unroll
  for (int off = 1; off < 16; off <<= 1)
#pragma unroll
    for (int r = 0; r < 4; r++)
      mrow[r] = fmaxf(mrow[r], __shfl_xor(mrow[r], off));

#pragma unroll
  for (int r = 0; r < 4; r++) lrow[r] = 0.0f;
#pragma unroll
  for (int ch = 0; ch < 5; ch++) {
    if (ch < c0) continue;
#pragma unroll
    for (int tn = 0; tn < 4; tn++)
#pragma unroll
      for (int r = 0; r < 4; r++) {
        float e = __expf(S[ch][tn][r] - mrow[r]);   // -inf -> 0
        S[ch][tn][r] = e;
        lrow[r] += e;
      }
  }
#pragma unroll
  for (int off = 1; off < 16; off <<= 1)
#pragma unroll
    for (int r = 0; r < 4; r++) lrow[r] += __shfl_xor(lrow[r], off);

  __syncthreads();   // all K reads done before Ps aliases the K region

  // ---- O = P V
  f32x4 Oacc[4];
#pragma unroll
  for (int td = 0; td < 4; td++) Oacc[td] = (f32x4)0.0f;

#pragma unroll
  for (int ch = 0; ch < 5; ch++) {
    if (ch < c0) continue;
    unsigned short* Ps = SH + (ch & 1) * 4608;      // ping-pong
#pragma unroll
    for (int tn = 0; tn < 4; tn++)
#pragma unroll
      for (int r = 0; r < 4; r++)
        Ps[(w * 16 + quad * 4 + r) * 68 + tn * 16 + l15] = f2bf(S[ch][tn][r]);
    asm volatile("s_waitcnt lgkmcnt(0)" ::: "memory");  // within-wave rows
#pragma unroll
    for (int ks = 0; ks < 2; ks++) {
      int off = (w * 16 + l15) * 68 + ks * 32 + quad * 8;
      bf16x4 plo = *(const bf16x4*)&Ps[off];
      bf16x4 phi = *(const bf16x4*)&Ps[off + 4];
      bf16x8 ap = __builtin_shufflevector(plo, phi, 0, 1, 2, 3, 4, 5, 6, 7);
      int kc = ks * 4 + quad;
#pragma unroll
      for (int td = 0; td < 4; td++) {
        bf16x8 bv = *(const bf16x8*)
            &SH[20480 + ch * 4096 + kc * 512 + (td * 16 + l15) * 8];
        Oacc[td] = __builtin_amdgcn_mfma_f32_16x16x32_bf16(
            ap, bv, Oacc[td], 0, 0, 0);
      }
    }
  }

  // ---- epilogue: y in proj's A-frag-packed layout (per-wave transpose)
  const int b = bh >> 4, h = bh & 15;
  float inv[4];
#pragma unroll
  for (int r = 0; r < 4; r++) inv[r] = 1.0f / lrow[r];
  unsigned short* Ot = SH + 10240;      // dead K region, row stride 72
#pragma unroll
  for (int td = 0; td < 4; td++)
#pragma unroll
    for (int r = 0; r < 4; r++)
      Ot[(w * 16 + quad * 4 + r) * 72 + td * 16 + l15] =
          f2bf(Oacc[td][r] * inv[r]);
  asm volatile("s_waitcnt lgkmcnt(0)" ::: "memory");
  const size_t rt = (size_t)((b * 2048 + q0) >> 4) + w;
#pragma unroll
  for (int f = 0; f < 2; f++) {
    bf16x8 fr = *(const bf16x8*)&Ot[(w * 16 + l15) * 72 + f * 32 + quad * 8];
    *(bf16x8*)&Ypk[(rt * 32 + h * 2 + f) * 512 + lane * 8] = fr;
  }
}

// ---------------------------------------------------------------------------
extern "C" void kernel_launch(void* const* d_in, const int* in_sizes, int n_in,
                              void* d_out, int out_size, void* d_ws, size_t ws_size,
                              hipStream_t stream) {
  const float* x     = (const float*)d_in[0];
  const float* wqkv  = (const float*)d_in[1];
  const float* wproj = (const float*)d_in[2];
  float* out = (float*)d_out;

  char* ws = (char*)d_ws;
  // [0,16M)   Apk (packed x; dead after QKV gemm) -> reused as Vt
  // [16,22M)  Wqkv bf16   [22,24M) Wproj bf16
  // [24,40M)  Qh   [40,56M) Kh   [56,72M) Vh   [72,88M) Ypk (packed y)
  unsigned short* apk    = (unsigned short*)(ws);
  unsigned short* vtb    = (unsigned short*)(ws);
  unsigned short* wqkvb  = (unsigned short*)(ws + (size_t)16 * 1024 * 1024);
  unsigned short* wprojb = (unsigned short*)(ws + (size_t)22 * 1024 * 1024);
  unsigned short* qh     = (unsigned short*)(ws + (size_t)24 * 1024 * 1024);
  unsigned short* kh     = (unsigned short*)(ws + (size_t)40 * 1024 * 1024);
  unsigned short* vh     = (unsigned short*)(ws + (size_t)56 * 1024 * 1024);
  unsigned short* ypk    = (unsigned short*)(ws + (size_t)72 * 1024 * 1024);

  // fused convert(W) + convert/pack(x)
  prep<<<4096 + 2048, 256, 0, stream>>>(
      x, wqkv, wproj, (__hip_bfloat16*)wqkvb, apk);

  // qkv = x @ Wqkv^T, scattered to head-major Q/K/V (Q pre-scaled)
  gemm_qkv<<<768, 512, 0, stream>>>(apk, wqkvb, qh, kh, vh);

  // V -> chunk-blocked transpose (into Apk region, now dead)
  transpose_v<<<dim3(32, 64), 256, 0, stream>>>(vh, vtb);

  // attention -> packed y
  attn_mfma<<<dim3(TT / 64, BB * HH), 256, 0, stream>>>(
      qh, kh, vtb, ypk);

  // out = y @ Wproj^T -> fp32
  gemm_proj<<<256, 512, 0, stream>>>(ypk, wprojb, out);
}

// Round 10
// 238.692 us; speedup vs baseline: 1.4892x; 1.0277x over previous
//
#include <hip/hip_runtime.h>
#include <hip/hip_bf16.h>
#include <math.h>

// Problem constants
#define BB 4
#define TT 2048
#define CC 1024
#define HH 16
#define DD 64
#define WW 256
#define MM (BB*TT)   // 8192 rows
#define NX (MM*CC)
#define NQ (3*CC*CC)
#define NP (CC*CC)

typedef __bf16 bf16x8 __attribute__((ext_vector_type(8)));
typedef __bf16 bf16x4 __attribute__((ext_vector_type(4)));
typedef float  f32x4  __attribute__((ext_vector_type(4)));

// async global->LDS 16B: LDS dest is wave-uniform base; HW adds lane*16
__device__ __forceinline__ void async_cp16(const void* g, void* l) {
  __builtin_amdgcn_global_load_lds(
      (const __attribute__((address_space(1))) void*)g,
      (__attribute__((address_space(3))) void*)l, 16, 0, 0);
}

__device__ __forceinline__ unsigned short f2bf(float v) {
  __hip_bfloat16 h = __float2bfloat16(v);
  return *(unsigned short*)&h;
}

// ---------------------------------------------------------------------------
// prep: fused (a) weight fp32->bf16 convert, (b) x convert+pack into
// MFMA A-fragment-major layout Apk[((rt*32+g)*64+lane)*8].
// ---------------------------------------------------------------------------
__global__ __launch_bounds__(256)
void prep(const float* __restrict__ x,
          const float* __restrict__ wq,
          const float* __restrict__ wp,
          __hip_bfloat16* __restrict__ wdst,
          unsigned short* __restrict__ Apk) {
  const int p = blockIdx.x;
  const int tid = threadIdx.x;
  if (p < 4096) {                       // ---- weight convert
    int i = (p * 256 + tid) * 4;
    const float* src; int off;
    if (i < NQ) { src = wq; off = i; }
    else        { src = wp; off = i - NQ; }
    float4 v = *(const float4*)(src + off);
    wdst[i + 0] = __float2bfloat16(v.x);
    wdst[i + 1] = __float2bfloat16(v.y);
    wdst[i + 2] = __float2bfloat16(v.z);
    wdst[i + 3] = __float2bfloat16(v.w);
    return;
  }
  // ---- x convert + pack (64 rows x 64 k per block)
  __shared__ __align__(16) unsigned short tile[64 * 72]; // stride 144B
  const int pid = p - 4096;
  const int bm = pid & 127;    // 0..127
  const int bk = pid >> 7;     // 0..15
  const int tr = tid >> 4;
  const int tc = (tid & 15) * 4;
#pragma unroll
  for (int i = 0; i < 4; i++) {
    int row = i * 16 + tr;
    float4 v = *(const float4*)&x[(size_t)(bm * 64 + row) * 1024 + bk * 64 + tc];
    tile[row * 72 + tc + 0] = f2bf(v.x);
    tile[row * 72 + tc + 1] = f2bf(v.y);
    tile[row * 72 + tc + 2] = f2bf(v.z);
    tile[row * 72 + tc + 3] = f2bf(v.w);
  }
  __syncthreads();
  const int w = tid >> 6, lane = tid & 63;
  const int quad = lane >> 4, l15 = lane & 15;
#pragma unroll
  for (int f = 0; f < 2; f++) {
    bf16x8 fr = *(const bf16x8*)&tile[(w * 16 + l15) * 72 + f * 32 + quad * 8];
    *(bf16x8*)&Apk[(((size_t)(bm * 4 + w) * 32) + bk * 2 + f) * 512 + lane * 8] = fr;
  }
}

// ---------------------------------------------------------------------------
// QKV GEMM round 10: 256x128 tile, 4 waves (256 thr), each wave 64 rows x
// 128 cols (tm=4, tn=8, acc=128 VGPR). Every A fragment read ONCE per block
// (r9 analysis: the 8-wave layout duplicated A 2x and was L2-BW-bound at
// ~77% of the 56 B/cyc/CU ceiling). A: direct packed-global->VGPR, depth-1
// prefetch. B: LDS dbuf BK=128, one barrier/stage. (256,2): 256 regs/wave,
// acc128+Af32+bfv32+addr fits w/o spill -- watch WRITE_SIZE.
// ---------------------------------------------------------------------------
__global__ __launch_bounds__(256, 2)
void gemm_qkv(const unsigned short* __restrict__ Apk,
              const unsigned short* __restrict__ Bw,
              unsigned short* __restrict__ Qh,
              unsigned short* __restrict__ Kh,
              unsigned short* __restrict__ Vh) {
  __shared__ __align__(16) unsigned short Bs0[16 * 1024]; // 32 KB
  __shared__ __align__(16) unsigned short Bs1[16 * 1024];

  const int id   = blockIdx.x;
  const int xcd  = id & 7;
  const int slot = id >> 3;        // 0..95
  const int mblk = slot / 3;       // 0..31
  const int nloc = slot % 3;       // 0..2
  const int n0 = (xcd * 3 + nloc) * 128;
  const int m0 = mblk * 256;

  const int tid  = threadIdx.x;
  const int w    = tid >> 6;       // 0..3: row-block of 64
  const int lane = tid & 63;
  const int quad = lane >> 4;
  const int l15  = lane & 15;

  f32x4 acc[4][8];
#pragma unroll
  for (int i = 0; i < 4; i++)
#pragma unroll
    for (int j = 0; j < 8; j++) acc[i][j] = (f32x4)0.0f;

  const unsigned short* abase =
      Apk + ((size_t)((m0 >> 4) + w * 4) * 32) * 512 + lane * 8;

  auto stageB = [&](int k0, unsigned short* bs) {
#pragma unroll
    for (int i = 0; i < 8; i++) {
      int idx  = w + 4 * i;        // 0..31
      int kc   = idx >> 1;         // 0..15
      int half = idx & 1;
      async_cp16(Bw + (size_t)(n0 + half * 64 + lane) * 1024 + k0 + kc * 8,
                 &bs[kc * 1024 + half * 512]);
    }
  };

  bf16x8 Af[2][4];                 // depth-1 prefetch
  auto loadA = [&](int g, bf16x8* fr) {
#pragma unroll
    for (int tm = 0; tm < 4; tm++)
      fr[tm] = *(const bf16x8*)(abase + ((size_t)(tm * 32 + g)) * 512);
  };

  loadA(0, Af[0]);
  stageB(0, Bs0);
  __syncthreads();

#pragma unroll
  for (int s = 0; s < 8; s++) {
    const unsigned short* bs = (s & 1) ? Bs1 : Bs0;
    if (s + 1 < 8) stageB((s + 1) * 128, (s & 1) ? Bs0 : Bs1);
#pragma unroll
    for (int sub = 0; sub < 4; sub++) {
      const int g = s * 4 + sub;
      if (g + 1 < 32) loadA(g + 1, Af[(g + 1) & 1]);
      const bf16x8* af = Af[g & 1];
#pragma unroll
      for (int tn = 0; tn < 8; tn++) {
        bf16x8 bfv = *(const bf16x8*)
            &bs[(sub * 4 + quad) * 1024 + (tn * 16 + l15) * 8];
#pragma unroll
        for (int tm = 0; tm < 4; tm++)
          acc[tm][tn] = __builtin_amdgcn_mfma_f32_16x16x32_bf16(
              af[tm], bfv, acc[tm][tn], 0, 0, 0);
      }
    }
    __syncthreads();
  }

  // scatter qkv: col -> (which, head, d); row -> (b, t)
#pragma unroll
  for (int tm = 0; tm < 4; tm++)
#pragma unroll
    for (int tn = 0; tn < 8; tn++) {
      int colb = n0 + tn * 16;
      int t3 = colb >> 10;
      int hh = (colb >> 6) & 15;
      int dd = (colb & 63) + l15;
      unsigned short* dst = (t3 == 0) ? Qh : ((t3 == 1) ? Kh : Vh);
      float sc = (t3 == 0) ? 0.125f : 1.0f;
#pragma unroll
      for (int r = 0; r < 4; r++) {
        int row = m0 + w * 64 + tm * 16 + quad * 4 + r;
        int b = row >> 11, tt = row & 2047;
        dst[((size_t)((b * 16 + hh) * 2048 + tt)) * 64 + dd] =
            f2bf(acc[tm][tn][r] * sc);
      }
    }
}

// ---------------------------------------------------------------------------
// Proj GEMM round 10: 128x128 tile, 4 waves, each wave 32 rows x 128 cols
// (tm=2, tn=8, acc=64). Grid 512 -> 2 blocks/CU (was 256 = 1/CU). A read
// once per block. n-panel per XCD.
// ---------------------------------------------------------------------------
__global__ __launch_bounds__(256, 2)
void gemm_proj(const unsigned short* __restrict__ Apk,
               const unsigned short* __restrict__ Bw,
               float* __restrict__ Co) {
  __shared__ __align__(16) unsigned short Bs0[16 * 1024];
  __shared__ __align__(16) unsigned short Bs1[16 * 1024];

  const int id = blockIdx.x;
  const int n0 = (id & 7) * 128;
  const int m0 = (id >> 3) * 128;

  const int tid  = threadIdx.x;
  const int w    = tid >> 6;       // 0..3: row-block of 32
  const int lane = tid & 63;
  const int quad = lane >> 4;
  const int l15  = lane & 15;

  f32x4 acc[2][8];
#pragma unroll
  for (int i = 0; i < 2; i++)
#pragma unroll
    for (int j = 0; j < 8; j++) acc[i][j] = (f32x4)0.0f;

  const unsigned short* abase =
      Apk + ((size_t)((m0 >> 4) + w * 2) * 32) * 512 + lane * 8;

  auto stageB = [&](int k0, unsigned short* bs) {
#pragma unroll
    for (int i = 0; i < 8; i++) {
      int idx  = w + 4 * i;
      int kc   = idx >> 1;
      int half = idx & 1;
      async_cp16(Bw + (size_t)(n0 + half * 64 + lane) * 1024 + k0 + kc * 8,
                 &bs[kc * 1024 + half * 512]);
    }
  };

  bf16x8 Af[2][2];
  auto loadA = [&](int g, bf16x8* fr) {
#pragma unroll
    for (int tm = 0; tm < 2; tm++)
      fr[tm] = *(const bf16x8*)(abase + ((size_t)(tm * 32 + g)) * 512);
  };

  loadA(0, Af[0]);
  stageB(0, Bs0);
  __syncthreads();

#pragma unroll
  for (int s = 0; s < 8; s++) {
    const unsigned short* bs = (s & 1) ? Bs1 : Bs0;
    if (s + 1 < 8) stageB((s + 1) * 128, (s & 1) ? Bs0 : Bs1);
#pragma unroll
    for (int sub = 0; sub < 4; sub++) {
      const int g = s * 4 + sub;
      if (g + 1 < 32) loadA(g + 1, Af[(g + 1) & 1]);
      const bf16x8* af = Af[g & 1];
#pragma unroll
      for (int tn = 0; tn < 8; tn++) {
        bf16x8 bfv = *(const bf16x8*)
            &bs[(sub * 4 + quad) * 1024 + (tn * 16 + l15) * 8];
#pragma unroll
        for (int tm = 0; tm < 2; tm++)
          acc[tm][tn] = __builtin_amdgcn_mfma_f32_16x16x32_bf16(
              af[tm], bfv, acc[tm][tn], 0, 0, 0);
      }
    }
    __syncthreads();
  }

#pragma unroll
  for (int tm = 0; tm < 2; tm++)
#pragma unroll
    for (int tn = 0; tn < 8; tn++)
#pragma unroll
      for (int r = 0; r < 4; r++) {
        int row = m0 + w * 32 + tm * 16 + quad * 4 + r;
        int col = n0 + tn * 16 + l15;
        Co[(size_t)row * 1024 + col] = acc[tm][tn][r];
      }
}

// ---------------------------------------------------------------------------
// Vh [bh][t][d] -> Vt chunk-blocked [bh][tc=32][d=64][tin=64]
// ---------------------------------------------------------------------------
__global__ __launch_bounds__(256)
void transpose_v(const unsigned short* __restrict__ Vh,
                 unsigned short* __restrict__ Vt) {
  __shared__ __align__(16) unsigned short tile[64 * 72];
  const int tid = threadIdx.x;
  const int tc = blockIdx.x, bh = blockIdx.y;
  const unsigned short* src = Vh + ((size_t)bh * 2048 + (size_t)tc * 64) * 64;
  for (int i = tid; i < 512; i += 256) {
    int r = i >> 3, ds = (i & 7) * 8;
    *(uint4*)&tile[r * 72 + ds] = *(const uint4*)&src[(size_t)r * 64 + ds];
  }
  __syncthreads();
  unsigned short* dst = Vt + (size_t)(bh * 32 + tc) * 4096;
  for (int i = tid; i < 512; i += 256) {
    int d = i >> 3, ts = (i & 7) * 8;
    unsigned int w0 = tile[(ts + 0) * 72 + d] | ((unsigned int)tile[(ts + 1) * 72 + d] << 16);
    unsigned int w1 = tile[(ts + 2) * 72 + d] | ((unsigned int)tile[(ts + 3) * 72 + d] << 16);
    unsigned int w2 = tile[(ts + 4) * 72 + d] | ((unsigned int)tile[(ts + 5) * 72 + d] << 16);
    unsigned int w3 = tile[(ts + 6) * 72 + d] | ((unsigned int)tile[(ts + 7) * 72 + d] << 16);
    uint4 o; o.x = w0; o.y = w1; o.z = w2; o.w = w3;
    *(uint4*)&dst[(size_t)d * 64 + ts] = o;
  }
}

// ---------------------------------------------------------------------------
// MFMA sliding-window flash attention, single-stage (r9-validated).
// ---------------------------------------------------------------------------
__global__ __launch_bounds__(256, 2)
void attn_mfma(const unsigned short* __restrict__ Qh,
               const unsigned short* __restrict__ Kh,
               const unsigned short* __restrict__ Vt,
               unsigned short* __restrict__ Ypk) {
  __shared__ __align__(16) unsigned short SH[40960];   // 80 KB

  const int tid  = threadIdx.x;
  const int w    = tid >> 6;
  const int lane = tid & 63;
  const int quad = lane >> 4;
  const int l15  = lane & 15;
  const int q0 = blockIdx.x * 64;
  const int bh = blockIdx.y;

  const int c0 = (q0 >= 256) ? 0 : (4 - (q0 >> 6));

  const unsigned short* Qg = Qh + ((size_t)bh * 2048 + q0) * 64;
  bf16x8 Qf[2];
#pragma unroll
  for (int fs = 0; fs < 2; fs++)
    Qf[fs] = *(const bf16x8*)(Qg + (w * 16 + l15) * 64 + fs * 32 + quad * 8);

  const unsigned short* Kg = Kh + (size_t)bh * 2048 * 64;
  const unsigned short* Vg = Vt + (size_t)bh * 32 * 4096;
  for (int ch = c0; ch < 5; ch++) {
    int sc = q0 - 256 + ch * 64;
#pragma unroll
    for (int i = 0; i < 2; i++) {
      int kc = w * 2 + i;
      async_cp16(Kg + (size_t)(sc + lane) * 64 + kc * 8,
                 &SH[ch * 4096 + kc * 512]);
      async_cp16(Vg + (size_t)(sc >> 6) * 4096 + lane * 64 + kc * 8,
                 &SH[20480 + ch * 4096 + kc * 512]);
    }
  }
  __syncthreads();

  f32x4 S[5][4];
#pragma unroll
  for (int ch = 0; ch < 5; ch++)
#pragma unroll
    for (int tn = 0; tn < 4; tn++) S[ch][tn] = (f32x4)0.0f;

#pragma unroll
  for (int ch = 0; ch < 5; ch++) {
    if (ch < c0) continue;
#pragma unroll
    for (int ks = 0; ks < 2; ks++) {
      int kc = ks * 4 + quad;
#pragma unroll
      for (int tn = 0; tn < 4; tn++) {
        bf16x8 bk = *(const bf16x8*)
            &SH[ch * 4096 + kc * 512 + (tn * 16 + l15) * 8];
        S[ch][tn] = __builtin_amdgcn_mfma_f32_16x16x32_bf16(
            Qf[ks], bk, S[ch][tn], 0, 0, 0);
      }
    }
  }

  const int qb = q0 + w * 16 + quad * 4;
  if (c0 == 0) {
#pragma unroll
    for (int tn = 0; tn < 4; tn++) {
      int j = q0 - 256 + tn * 16 + l15;
#pragma unroll
      for (int r = 0; r < 4; r++)
        if (qb + r > j + (WW - 1)) S[0][tn][r] = -__builtin_inff();
    }
  }
#pragma unroll
  for (int tn = 0; tn < 4; tn++) {
    int j = q0 + tn * 16 + l15;
#pragma unroll
    for (int r = 0; r < 4; r++)
      if (j > qb + r) S[4][tn][r] = -__builtin_inff();
  }

  float mrow[4], lrow[4];
#pragma unroll
  for (int r = 0; r < 4; r++) mrow[r] = -__builtin_inff();
#pragma unroll
  for (int ch = 0; ch < 5; ch++) {
    if (ch < c0) continue;
#pragma unroll
    for (int tn = 0; tn < 4; tn++)
#pragma unroll
      for (int r = 0; r < 4; r++)
        mrow[r] = fmaxf(mrow[r], S[ch][tn][r]);
  }
#pragma unroll
  for (int off = 1; off < 16; off <<= 1)
#pragma unroll
    for (int r = 0; r < 4; r++)
      mrow[r] = fmaxf(mrow[r], __shfl_xor(mrow[r], off));

#pragma unroll
  for (int r = 0; r < 4; r++) lrow[r] = 0.0f;
#pragma unroll
  for (int ch = 0; ch < 5; ch++) {
    if (ch < c0) continue;
#pragma unroll
    for (int tn = 0; tn < 4; tn++)
#pragma unroll
      for (int r = 0; r < 4; r++) {
        float e = __expf(S[ch][tn][r] - mrow[r]);
        S[ch][tn][r] = e;
        lrow[r] += e;
      }
  }
#pragma unroll
  for (int off = 1; off < 16; off <<= 1)
#pragma unroll
    for (int r = 0; r < 4; r++) lrow[r] += __shfl_xor(lrow[r], off);

  __syncthreads();   // all K reads done before Ps aliases the K region

  f32x4 Oacc[4];
#pragma unroll
  for (int td = 0; td < 4; td++) Oacc[td] = (f32x4)0.0f;

#pragma unroll
  for (int ch = 0; ch < 5; ch++) {
    if (ch < c0) continue;
    unsigned short* Ps = SH + (ch & 1) * 4608;
#pragma unroll
    for (int tn = 0; tn < 4; tn++)
#pragma unroll
      for (int r = 0; r < 4; r++)
        Ps[(w * 16 + quad * 4 + r) * 68 + tn * 16 + l15] = f2bf(S[ch][tn][r]);
    asm volatile("s_waitcnt lgkmcnt(0)" ::: "memory");
#pragma unroll
    for (int ks = 0; ks < 2; ks++) {
      int off = (w * 16 + l15) * 68 + ks * 32 + quad * 8;
      bf16x4 plo = *(const bf16x4*)&Ps[off];
      bf16x4 phi = *(const bf16x4*)&Ps[off + 4];
      bf16x8 ap = __builtin_shufflevector(plo, phi, 0, 1, 2, 3, 4, 5, 6, 7);
      int kc = ks * 4 + quad;
#pragma unroll
      for (int td = 0; td < 4; td++) {
        bf16x8 bv = *(const bf16x8*)
            &SH[20480 + ch * 4096 + kc * 512 + (td * 16 + l15) * 8];
        Oacc[td] = __builtin_amdgcn_mfma_f32_16x16x32_bf16(
            ap, bv, Oacc[td], 0, 0, 0);
      }
    }
  }

  const int b = bh >> 4, h = bh & 15;
  float inv[4];
#pragma unroll
  for (int r = 0; r < 4; r++) inv[r] = 1.0f / lrow[r];
  unsigned short* Ot = SH + 10240;
#pragma unroll
  for (int td = 0; td < 4; td++)
#pragma unroll
    for (int r = 0; r < 4; r++)
      Ot[(w * 16 + quad * 4 + r) * 72 + td * 16 + l15] =
          f2bf(Oacc[td][r] * inv[r]);
  asm volatile("s_waitcnt lgkmcnt(0)" ::: "memory");
  const size_t rt = (size_t)((b * 2048 + q0) >> 4) + w;
#pragma unroll
  for (int f = 0; f < 2; f++) {
    bf16x8 fr = *(const bf16x8*)&Ot[(w * 16 + l15) * 72 + f * 32 + quad * 8];
    *(bf16x8*)&Ypk[(rt * 32 + h * 2 + f) * 512 + lane * 8] = fr;
  }
}

// ---------------------------------------------------------------------------
extern "C" void kernel_launch(void* const* d_in, const int* in_sizes, int n_in,
                              void* d_out, int out_size, void* d_ws, size_t ws_size,
                              hipStream_t stream) {
  const float* x     = (const float*)d_in[0];
  const float* wqkv  = (const float*)d_in[1];
  const float* wproj = (const float*)d_in[2];
  float* out = (float*)d_out;

  char* ws = (char*)d_ws;
  unsigned short* apk    = (unsigned short*)(ws);
  unsigned short* vtb    = (unsigned short*)(ws);
  unsigned short* wqkvb  = (unsigned short*)(ws + (size_t)16 * 1024 * 1024);
  unsigned short* wprojb = (unsigned short*)(ws + (size_t)22 * 1024 * 1024);
  unsigned short* qh     = (unsigned short*)(ws + (size_t)24 * 1024 * 1024);
  unsigned short* kh     = (unsigned short*)(ws + (size_t)40 * 1024 * 1024);
  unsigned short* vh     = (unsigned short*)(ws + (size_t)56 * 1024 * 1024);
  unsigned short* ypk    = (unsigned short*)(ws + (size_t)72 * 1024 * 1024);

  prep<<<4096 + 2048, 256, 0, stream>>>(
      x, wqkv, wproj, (__hip_bfloat16*)wqkvb, apk);

  gemm_qkv<<<768, 256, 0, stream>>>(apk, wqkvb, qh, kh, vh);

  transpose_v<<<dim3(32, 64), 256, 0, stream>>>(vh, vtb);

  attn_mfma<<<dim3(TT / 64, BB * HH), 256, 0, stream>>>(
      qh, kh, vtb, ypk);

  gemm_proj<<<512, 256, 0, stream>>>(ypk, wprojb, out);
}

// Round 12
// 230.816 us; speedup vs baseline: 1.5400x; 1.0341x over previous
//
#include <hip/hip_runtime.h>
#include <hip/hip_bf16.h>
#include <math.h>

// Problem constants
#define BB 4
#define TT 2048
#define CC 1024
#define HH 16
#define DD 64
#define WW 256
#define MM (BB*TT)   // 8192 rows
#define NX (MM*CC)
#define NQ (3*CC*CC)
#define NP (CC*CC)

typedef __bf16 bf16x8 __attribute__((ext_vector_type(8)));
typedef __bf16 bf16x4 __attribute__((ext_vector_type(4)));
typedef float  f32x4  __attribute__((ext_vector_type(4)));

// async global->LDS 16B: LDS dest is wave-uniform base; HW adds lane*16
__device__ __forceinline__ void async_cp16(const void* g, void* l) {
  __builtin_amdgcn_global_load_lds(
      (const __attribute__((address_space(1))) void*)g,
      (__attribute__((address_space(3))) void*)l, 16, 0, 0);
}

__device__ __forceinline__ unsigned short f2bf(float v) {
  __hip_bfloat16 h = __float2bfloat16(v);
  return *(unsigned short*)&h;
}

// ---------------------------------------------------------------------------
// prep: fused (a) weight fp32->bf16 convert, (b) x convert+pack into
// MFMA A-fragment-major layout Apk[((rt*32+g)*64+lane)*8].
// ---------------------------------------------------------------------------
__global__ __launch_bounds__(256)
void prep(const float* __restrict__ x,
          const float* __restrict__ wq,
          const float* __restrict__ wp,
          __hip_bfloat16* __restrict__ wdst,
          unsigned short* __restrict__ Apk) {
  const int p = blockIdx.x;
  const int tid = threadIdx.x;
  if (p < 4096) {                       // ---- weight convert
    int i = (p * 256 + tid) * 4;
    const float* src; int off;
    if (i < NQ) { src = wq; off = i; }
    else        { src = wp; off = i - NQ; }
    float4 v = *(const float4*)(src + off);
    wdst[i + 0] = __float2bfloat16(v.x);
    wdst[i + 1] = __float2bfloat16(v.y);
    wdst[i + 2] = __float2bfloat16(v.z);
    wdst[i + 3] = __float2bfloat16(v.w);
    return;
  }
  // ---- x convert + pack (64 rows x 64 k per block)
  __shared__ __align__(16) unsigned short tile[64 * 72]; // stride 144B
  const int pid = p - 4096;
  const int bm = pid & 127;
  const int bk = pid >> 7;
  const int tr = tid >> 4;
  const int tc = (tid & 15) * 4;
#pragma unroll
  for (int i = 0; i < 4; i++) {
    int row = i * 16 + tr;
    float4 v = *(const float4*)&x[(size_t)(bm * 64 + row) * 1024 + bk * 64 + tc];
    tile[row * 72 + tc + 0] = f2bf(v.x);
    tile[row * 72 + tc + 1] = f2bf(v.y);
    tile[row * 72 + tc + 2] = f2bf(v.z);
    tile[row * 72 + tc + 3] = f2bf(v.w);
  }
  __syncthreads();
  const int w = tid >> 6, lane = tid & 63;
  const int quad = lane >> 4, l15 = lane & 15;
#pragma unroll
  for (int f = 0; f < 2; f++) {
    bf16x8 fr = *(const bf16x8*)&tile[(w * 16 + l15) * 72 + f * 32 + quad * 8];
    *(bf16x8*)&Apk[(((size_t)(bm * 4 + w) * 32) + bk * 2 + f) * 512 + lane * 8] = fr;
  }
}

// ---------------------------------------------------------------------------
// QKV GEMM (r11 structure, SCALE FIX): 256x128 tile, 4 waves, wave=64x128,
// acc 128 AGPR, depth-2 A prefetch (ring-3). V-blocks write Vt transposed
// directly via per-wave LDS transpose in dead Bs.  ** r11 bug: Q's 0.125
// pre-scale was declared but not applied -> absmax 4.0; restored here. **
// ---------------------------------------------------------------------------
__global__ __launch_bounds__(256, 2)
void gemm_qkv(const unsigned short* __restrict__ Apk,
              const unsigned short* __restrict__ Bw,
              unsigned short* __restrict__ Qh,
              unsigned short* __restrict__ Kh,
              unsigned short* __restrict__ Vt) {
  __shared__ __align__(16) unsigned short Bs0[16 * 1024]; // 32 KB
  __shared__ __align__(16) unsigned short Bs1[16 * 1024];

  const int id   = blockIdx.x;
  const int xcd  = id & 7;
  const int slot = id >> 3;
  const int mblk = slot / 3;
  const int nloc = slot % 3;
  const int n0 = (xcd * 3 + nloc) * 128;
  const int m0 = mblk * 256;

  const int tid  = threadIdx.x;
  const int w    = tid >> 6;       // 0..3: row-block of 64
  const int lane = tid & 63;
  const int quad = lane >> 4;
  const int l15  = lane & 15;

  f32x4 acc[4][8];
#pragma unroll
  for (int i = 0; i < 4; i++)
#pragma unroll
    for (int j = 0; j < 8; j++) acc[i][j] = (f32x4)0.0f;

  const unsigned short* abase =
      Apk + ((size_t)((m0 >> 4) + w * 4) * 32) * 512 + lane * 8;

  auto stageB = [&](int k0, unsigned short* bs) {
#pragma unroll
    for (int i = 0; i < 8; i++) {
      int idx  = w + 4 * i;
      int kc   = idx >> 1;
      int half = idx & 1;
      async_cp16(Bw + (size_t)(n0 + half * 64 + lane) * 1024 + k0 + kc * 8,
                 &bs[kc * 1024 + half * 512]);
    }
  };

  bf16x8 Af[3][4];                 // depth-2 prefetch ring
  auto loadA = [&](int g, bf16x8* fr) {
#pragma unroll
    for (int tm = 0; tm < 4; tm++)
      fr[tm] = *(const bf16x8*)(abase + ((size_t)(tm * 32 + g)) * 512);
  };

  loadA(0, Af[0]);
  loadA(1, Af[1]);
  stageB(0, Bs0);
  __syncthreads();

#pragma unroll
  for (int s = 0; s < 8; s++) {
    const unsigned short* bs = (s & 1) ? Bs1 : Bs0;
    if (s + 1 < 8) stageB((s + 1) * 128, (s & 1) ? Bs0 : Bs1);
#pragma unroll
    for (int sub = 0; sub < 4; sub++) {
      const int g = s * 4 + sub;
      if (g + 2 < 32) loadA(g + 2, Af[(g + 2) % 3]);
      const bf16x8* af = Af[g % 3];
#pragma unroll
      for (int tn = 0; tn < 8; tn++) {
        bf16x8 bfv = *(const bf16x8*)
            &bs[(sub * 4 + quad) * 1024 + (tn * 16 + l15) * 8];
#pragma unroll
        for (int tm = 0; tm < 4; tm++)
          acc[tm][tn] = __builtin_amdgcn_mfma_f32_16x16x32_bf16(
              af[tm], bfv, acc[tm][tn], 0, 0, 0);
      }
    }
    __syncthreads();
  }

  const int t3 = n0 >> 10;              // block-uniform: 0=Q,1=K,2=V
  if (t3 < 2) {
    // ---- Q/K scatter to head-major [b*h][t][d]
    unsigned short* dst0 = (t3 == 0) ? Qh : Kh;
    const float sc = (t3 == 0) ? 0.125f : 1.0f;   // 1/sqrt(64), exact
#pragma unroll
    for (int tm = 0; tm < 4; tm++)
#pragma unroll
      for (int tn = 0; tn < 8; tn++) {
        int colb = n0 + tn * 16;
        int hh = (colb >> 6) & 15;
        int dd = (colb & 63) + l15;
#pragma unroll
        for (int r = 0; r < 4; r++) {
          int row = m0 + w * 64 + tm * 16 + quad * 4 + r;
          int b = row >> 11, tt = row & 2047;
          dst0[((size_t)((b * 16 + hh) * 2048 + tt)) * 64 + dd] =
              f2bf(acc[tm][tn][r] * sc);          // <-- the r11 fix
        }
      }
  } else {
    // ---- V: per-wave LDS transpose -> Vt [bh][tc][d 64][tin 64]
    unsigned short* T = (w < 3) ? (Bs0 + w * 4608) : Bs1;  // 64x72 tile
    const int b    = (m0 + w * 64) >> 11;
    const int tc_g = ((m0 & 2047) >> 6) + w;
    const int h0   = (n0 >> 6) & 15;
#pragma unroll
    for (int hp = 0; hp < 2; hp++) {
#pragma unroll
      for (int tnl = 0; tnl < 4; tnl++)
#pragma unroll
        for (int tm = 0; tm < 4; tm++)
#pragma unroll
          for (int r = 0; r < 4; r++)
            T[(tnl * 16 + l15) * 72 + tm * 16 + quad * 4 + r] =
                f2bf(acc[tm][hp * 4 + tnl][r]);
      asm volatile("s_waitcnt lgkmcnt(0)" ::: "memory");  // wave-private
      const size_t base =
          ((size_t)((b * 16 + h0 + hp) * 32 + tc_g)) * 4096;
#pragma unroll
      for (int i = 0; i < 8; i++) {
        int d   = i * 8 + (lane >> 3);
        int tin = (lane & 7) * 8;
        bf16x8 v = *(const bf16x8*)&T[d * 72 + tin];
        *(bf16x8*)&Vt[base + (size_t)d * 64 + tin] = v;   // coalesced 1KB
      }
      // DS ops are in-order per wave: next hp's writes can't pass reads.
    }
  }
}

// ---------------------------------------------------------------------------
// Proj GEMM: r10 shape + depth-2 A prefetch.
// ---------------------------------------------------------------------------
__global__ __launch_bounds__(256, 2)
void gemm_proj(const unsigned short* __restrict__ Apk,
               const unsigned short* __restrict__ Bw,
               float* __restrict__ Co) {
  __shared__ __align__(16) unsigned short Bs0[16 * 1024];
  __shared__ __align__(16) unsigned short Bs1[16 * 1024];

  const int id = blockIdx.x;
  const int n0 = (id & 7) * 128;
  const int m0 = (id >> 3) * 128;

  const int tid  = threadIdx.x;
  const int w    = tid >> 6;
  const int lane = tid & 63;
  const int quad = lane >> 4;
  const int l15  = lane & 15;

  f32x4 acc[2][8];
#pragma unroll
  for (int i = 0; i < 2; i++)
#pragma unroll
    for (int j = 0; j < 8; j++) acc[i][j] = (f32x4)0.0f;

  const unsigned short* abase =
      Apk + ((size_t)((m0 >> 4) + w * 2) * 32) * 512 + lane * 8;

  auto stageB = [&](int k0, unsigned short* bs) {
#pragma unroll
    for (int i = 0; i < 8; i++) {
      int idx  = w + 4 * i;
      int kc   = idx >> 1;
      int half = idx & 1;
      async_cp16(Bw + (size_t)(n0 + half * 64 + lane) * 1024 + k0 + kc * 8,
                 &bs[kc * 1024 + half * 512]);
    }
  };

  bf16x8 Af[3][2];                 // depth-2 prefetch ring
  auto loadA = [&](int g, bf16x8* fr) {
#pragma unroll
    for (int tm = 0; tm < 2; tm++)
      fr[tm] = *(const bf16x8*)(abase + ((size_t)(tm * 32 + g)) * 512);
  };

  loadA(0, Af[0]);
  loadA(1, Af[1]);
  stageB(0, Bs0);
  __syncthreads();

#pragma unroll
  for (int s = 0; s < 8; s++) {
    const unsigned short* bs = (s & 1) ? Bs1 : Bs0;
    if (s + 1 < 8) stageB((s + 1) * 128, (s & 1) ? Bs0 : Bs1);
#pragma unroll
    for (int sub = 0; sub < 4; sub++) {
      const int g = s * 4 + sub;
      if (g + 2 < 32) loadA(g + 2, Af[(g + 2) % 3]);
      const bf16x8* af = Af[g % 3];
#pragma unroll
      for (int tn = 0; tn < 8; tn++) {
        bf16x8 bfv = *(const bf16x8*)
            &bs[(sub * 4 + quad) * 1024 + (tn * 16 + l15) * 8];
#pragma unroll
        for (int tm = 0; tm < 2; tm++)
          acc[tm][tn] = __builtin_amdgcn_mfma_f32_16x16x32_bf16(
              af[tm], bfv, acc[tm][tn], 0, 0, 0);
      }
    }
    __syncthreads();
  }

#pragma unroll
  for (int tm = 0; tm < 2; tm++)
#pragma unroll
    for (int tn = 0; tn < 8; tn++)
#pragma unroll
      for (int r = 0; r < 4; r++) {
        int row = m0 + w * 32 + tm * 16 + quad * 4 + r;
        int col = n0 + tn * 16 + l15;
        Co[(size_t)row * 1024 + col] = acc[tm][tn][r];
      }
}

// ---------------------------------------------------------------------------
// MFMA sliding-window flash attention, single-stage (r9-validated).
// ---------------------------------------------------------------------------
__global__ __launch_bounds__(256, 2)
void attn_mfma(const unsigned short* __restrict__ Qh,
               const unsigned short* __restrict__ Kh,
               const unsigned short* __restrict__ Vt,
               unsigned short* __restrict__ Ypk) {
  __shared__ __align__(16) unsigned short SH[40960];   // 80 KB

  const int tid  = threadIdx.x;
  const int w    = tid >> 6;
  const int lane = tid & 63;
  const int quad = lane >> 4;
  const int l15  = lane & 15;
  const int q0 = blockIdx.x * 64;
  const int bh = blockIdx.y;

  const int c0 = (q0 >= 256) ? 0 : (4 - (q0 >> 6));

  const unsigned short* Qg = Qh + ((size_t)bh * 2048 + q0) * 64;
  bf16x8 Qf[2];
#pragma unroll
  for (int fs = 0; fs < 2; fs++)
    Qf[fs] = *(const bf16x8*)(Qg + (w * 16 + l15) * 64 + fs * 32 + quad * 8);

  const unsigned short* Kg = Kh + (size_t)bh * 2048 * 64;
  const unsigned short* Vg = Vt + (size_t)bh * 32 * 4096;
  for (int ch = c0; ch < 5; ch++) {
    int sc = q0 - 256 + ch * 64;
#pragma unroll
    for (int i = 0; i < 2; i++) {
      int kc = w * 2 + i;
      async_cp16(Kg + (size_t)(sc + lane) * 64 + kc * 8,
                 &SH[ch * 4096 + kc * 512]);
      async_cp16(Vg + (size_t)(sc >> 6) * 4096 + lane * 64 + kc * 8,
                 &SH[20480 + ch * 4096 + kc * 512]);
    }
  }
  __syncthreads();

  f32x4 S[5][4];
#pragma unroll
  for (int ch = 0; ch < 5; ch++)
#pragma unroll
    for (int tn = 0; tn < 4; tn++) S[ch][tn] = (f32x4)0.0f;

#pragma unroll
  for (int ch = 0; ch < 5; ch++) {
    if (ch < c0) continue;
#pragma unroll
    for (int ks = 0; ks < 2; ks++) {
      int kc = ks * 4 + quad;
#pragma unroll
      for (int tn = 0; tn < 4; tn++) {
        bf16x8 bk = *(const bf16x8*)
            &SH[ch * 4096 + kc * 512 + (tn * 16 + l15) * 8];
        S[ch][tn] = __builtin_amdgcn_mfma_f32_16x16x32_bf16(
            Qf[ks], bk, S[ch][tn], 0, 0, 0);
      }
    }
  }

  const int qb = q0 + w * 16 + quad * 4;
  if (c0 == 0) {
#pragma unroll
    for (int tn = 0; tn < 4; tn++) {
      int j = q0 - 256 + tn * 16 + l15;
#pragma unroll
      for (int r = 0; r < 4; r++)
        if (qb + r > j + (WW - 1)) S[0][tn][r] = -__builtin_inff();
    }
  }
#pragma unroll
  for (int tn = 0; tn < 4; tn++) {
    int j = q0 + tn * 16 + l15;
#pragma unroll
    for (int r = 0; r < 4; r++)
      if (j > qb + r) S[4][tn][r] = -__builtin_inff();
  }

  float mrow[4], lrow[4];
#pragma unroll
  for (int r = 0; r < 4; r++) mrow[r] = -__builtin_inff();
#pragma unroll
  for (int ch = 0; ch < 5; ch++) {
    if (ch < c0) continue;
#pragma unroll
    for (int tn = 0; tn < 4; tn++)
#pragma unroll
      for (int r = 0; r < 4; r++)
        mrow[r] = fmaxf(mrow[r], S[ch][tn][r]);
  }
#pragma unroll
  for (int off = 1; off < 16; off <<= 1)
#pragma unroll
    for (int r = 0; r < 4; r++)
      mrow[r] = fmaxf(mrow[r], __shfl_xor(mrow[r], off));

#pragma unroll
  for (int r = 0; r < 4; r++) lrow[r] = 0.0f;
#pragma unroll
  for (int ch = 0; ch < 5; ch++) {
    if (ch < c0) continue;
#pragma unroll
    for (int tn = 0; tn < 4; tn++)
#pragma unroll
      for (int r = 0; r < 4; r++) {
        float e = __expf(S[ch][tn][r] - mrow[r]);
        S[ch][tn][r] = e;
        lrow[r] += e;
      }
  }
#pragma unroll
  for (int off = 1; off < 16; off <<= 1)
#pragma unroll
    for (int r = 0; r < 4; r++) lrow[r] += __shfl_xor(lrow[r], off);

  __syncthreads();   // all K reads done before Ps aliases the K region

  f32x4 Oacc[4];
#pragma unroll
  for (int td = 0; td < 4; td++) Oacc[td] = (f32x4)0.0f;

#pragma unroll
  for (int ch = 0; ch < 5; ch++) {
    if (ch < c0) continue;
    unsigned short* Ps = SH + (ch & 1) * 4608;
#pragma unroll
    for (int tn = 0; tn < 4; tn++)
#pragma unroll
      for (int r = 0; r < 4; r++)
        Ps[(w * 16 + quad * 4 + r) * 68 + tn * 16 + l15] = f2bf(S[ch][tn][r]);
    asm volatile("s_waitcnt lgkmcnt(0)" ::: "memory");
#pragma unroll
    for (int ks = 0; ks < 2; ks++) {
      int off = (w * 16 + l15) * 68 + ks * 32 + quad * 8;
      bf16x4 plo = *(const bf16x4*)&Ps[off];
      bf16x4 phi = *(const bf16x4*)&Ps[off + 4];
      bf16x8 ap = __builtin_shufflevector(plo, phi, 0, 1, 2, 3, 4, 5, 6, 7);
      int kc = ks * 4 + quad;
#pragma unroll
      for (int td = 0; td < 4; td++) {
        bf16x8 bv = *(const bf16x8*)
            &SH[20480 + ch * 4096 + kc * 512 + (td * 16 + l15) * 8];
        Oacc[td] = __builtin_amdgcn_mfma_f32_16x16x32_bf16(
            ap, bv, Oacc[td], 0, 0, 0);
      }
    }
  }

  const int b = bh >> 4, h = bh & 15;
  float inv[4];
#pragma unroll
  for (int r = 0; r < 4; r++) inv[r] = 1.0f / lrow[r];
  unsigned short* Ot = SH + 10240;
#pragma unroll
  for (int td = 0; td < 4; td++)
#pragma unroll
    for (int r = 0; r < 4; r++)
      Ot[(w * 16 + quad * 4 + r) * 72 + td * 16 + l15] =
          f2bf(Oacc[td][r] * inv[r]);
  asm volatile("s_waitcnt lgkmcnt(0)" ::: "memory");
  const size_t rt = (size_t)((b * 2048 + q0) >> 4) + w;
#pragma unroll
  for (int f = 0; f < 2; f++) {
    bf16x8 fr = *(const bf16x8*)&Ot[(w * 16 + l15) * 72 + f * 32 + quad * 8];
    *(bf16x8*)&Ypk[(rt * 32 + h * 2 + f) * 512 + lane * 8] = fr;
  }
}

// ---------------------------------------------------------------------------
extern "C" void kernel_launch(void* const* d_in, const int* in_sizes, int n_in,
                              void* d_out, int out_size, void* d_ws, size_t ws_size,
                              hipStream_t stream) {
  const float* x     = (const float*)d_in[0];
  const float* wqkv  = (const float*)d_in[1];
  const float* wproj = (const float*)d_in[2];
  float* out = (float*)d_out;

  char* ws = (char*)d_ws;
  // [0,16M)   Apk (packed x)
  // [16,22M)  Wqkv bf16   [22,24M) Wproj bf16
  // [24,40M)  Qh   [40,56M) Kh   [56,72M) Vt   [72,88M) Ypk (packed y)
  unsigned short* apk    = (unsigned short*)(ws);
  unsigned short* wqkvb  = (unsigned short*)(ws + (size_t)16 * 1024 * 1024);
  unsigned short* wprojb = (unsigned short*)(ws + (size_t)22 * 1024 * 1024);
  unsigned short* qh     = (unsigned short*)(ws + (size_t)24 * 1024 * 1024);
  unsigned short* kh     = (unsigned short*)(ws + (size_t)40 * 1024 * 1024);
  unsigned short* vt     = (unsigned short*)(ws + (size_t)56 * 1024 * 1024);
  unsigned short* ypk    = (unsigned short*)(ws + (size_t)72 * 1024 * 1024);

  prep<<<4096 + 2048, 256, 0, stream>>>(
      x, wqkv, wproj, (__hip_bfloat16*)wqkvb, apk);

  // qkv = x @ Wqkv^T -> Qh/Kh (head-major) + Vt (transposed, fused)
  gemm_qkv<<<768, 256, 0, stream>>>(apk, wqkvb, qh, kh, vt);

  attn_mfma<<<dim3(TT / 64, BB * HH), 256, 0, stream>>>(
      qh, kh, vt, ypk);

  gemm_proj<<<512, 256, 0, stream>>>(ypk, wprojb, out);
}

// Round 13
// 226.012 us; speedup vs baseline: 1.5727x; 1.0213x over previous
//
#include <hip/hip_runtime.h>
#include <hip/hip_bf16.h>
#include <math.h>

// Problem constants
#define BB 4
#define TT 2048
#define CC 1024
#define HH 16
#define DD 64
#define WW 256
#define MM (BB*TT)   // 8192 rows
#define NX (MM*CC)
#define NQ (3*CC*CC)
#define NP (CC*CC)

typedef __bf16 bf16x8 __attribute__((ext_vector_type(8)));
typedef __bf16 bf16x4 __attribute__((ext_vector_type(4)));
typedef float  f32x4  __attribute__((ext_vector_type(4)));

// async global->LDS 16B: LDS dest is wave-uniform base; HW adds lane*16
__device__ __forceinline__ void async_cp16(const void* g, void* l) {
  __builtin_amdgcn_global_load_lds(
      (const __attribute__((address_space(1))) void*)g,
      (__attribute__((address_space(3))) void*)l, 16, 0, 0);
}

__device__ __forceinline__ unsigned short f2bf(float v) {
  __hip_bfloat16 h = __float2bfloat16(v);
  return *(unsigned short*)&h;
}

// ---------------------------------------------------------------------------
// prep: fused (a) weight fp32->bf16 convert, (b) x convert+pack into
// MFMA A-fragment-major layout Apk[((rt*32+g)*64+lane)*8].
// ---------------------------------------------------------------------------
__global__ __launch_bounds__(256)
void prep(const float* __restrict__ x,
          const float* __restrict__ wq,
          const float* __restrict__ wp,
          __hip_bfloat16* __restrict__ wdst,
          unsigned short* __restrict__ Apk) {
  const int p = blockIdx.x;
  const int tid = threadIdx.x;
  if (p < 4096) {                       // ---- weight convert
    int i = (p * 256 + tid) * 4;
    const float* src; int off;
    if (i < NQ) { src = wq; off = i; }
    else        { src = wp; off = i - NQ; }
    float4 v = *(const float4*)(src + off);
    wdst[i + 0] = __float2bfloat16(v.x);
    wdst[i + 1] = __float2bfloat16(v.y);
    wdst[i + 2] = __float2bfloat16(v.z);
    wdst[i + 3] = __float2bfloat16(v.w);
    return;
  }
  // ---- x convert + pack (64 rows x 64 k per block)
  __shared__ __align__(16) unsigned short tile[64 * 72]; // stride 144B
  const int pid = p - 4096;
  const int bm = pid & 127;
  const int bk = pid >> 7;
  const int tr = tid >> 4;
  const int tc = (tid & 15) * 4;
#pragma unroll
  for (int i = 0; i < 4; i++) {
    int row = i * 16 + tr;
    float4 v = *(const float4*)&x[(size_t)(bm * 64 + row) * 1024 + bk * 64 + tc];
    tile[row * 72 + tc + 0] = f2bf(v.x);
    tile[row * 72 + tc + 1] = f2bf(v.y);
    tile[row * 72 + tc + 2] = f2bf(v.z);
    tile[row * 72 + tc + 3] = f2bf(v.w);
  }
  __syncthreads();
  const int w = tid >> 6, lane = tid & 63;
  const int quad = lane >> 4, l15 = lane & 15;
#pragma unroll
  for (int f = 0; f < 2; f++) {
    bf16x8 fr = *(const bf16x8*)&tile[(w * 16 + l15) * 72 + f * 32 + quad * 8];
    *(bf16x8*)&Apk[(((size_t)(bm * 4 + w) * 32) + bk * 2 + f) * 512 + lane * 8] = fr;
  }
}

// ---------------------------------------------------------------------------
// QKV GEMM (round 13 = r12 datapath, L2-RESIDENCY SWIZZLE):
// Each XCD now owns a contiguous m-range (4 m-blocks = 2 MB of Apk, fits
// its 4 MB L2) and iterates ALL 24 n-panels over it -- A direct-loads
// become ~200cyc L2 hits, inside the depth-2 prefetch reach (~310cyc).
// r12's swizzle gave every XCD the full 16 MB Apk -> L3-latency stalls
// (FETCH 74.8MB = 3.4x unique, MfmaUtil stuck at 29%).
// ---------------------------------------------------------------------------
__global__ __launch_bounds__(256, 2)
void gemm_qkv(const unsigned short* __restrict__ Apk,
              const unsigned short* __restrict__ Bw,
              unsigned short* __restrict__ Qh,
              unsigned short* __restrict__ Kh,
              unsigned short* __restrict__ Vt) {
  __shared__ __align__(16) unsigned short Bs0[16 * 1024]; // 32 KB
  __shared__ __align__(16) unsigned short Bs1[16 * 1024];

  const int id   = blockIdx.x;
  const int xcd  = id & 7;
  const int slot = id >> 3;        // 0..95
  const int mloc = slot / 24;      // 0..3   (XCD-local m-block)
  const int nloc = slot % 24;      // 0..23  (n-panels stream over L2-hot A)
  const int m0 = (xcd * 4 + mloc) * 256;
  const int n0 = nloc * 128;

  const int tid  = threadIdx.x;
  const int w    = tid >> 6;       // 0..3: row-block of 64
  const int lane = tid & 63;
  const int quad = lane >> 4;
  const int l15  = lane & 15;

  f32x4 acc[4][8];
#pragma unroll
  for (int i = 0; i < 4; i++)
#pragma unroll
    for (int j = 0; j < 8; j++) acc[i][j] = (f32x4)0.0f;

  const unsigned short* abase =
      Apk + ((size_t)((m0 >> 4) + w * 4) * 32) * 512 + lane * 8;

  auto stageB = [&](int k0, unsigned short* bs) {
#pragma unroll
    for (int i = 0; i < 8; i++) {
      int idx  = w + 4 * i;
      int kc   = idx >> 1;
      int half = idx & 1;
      async_cp16(Bw + (size_t)(n0 + half * 64 + lane) * 1024 + k0 + kc * 8,
                 &bs[kc * 1024 + half * 512]);
    }
  };

  bf16x8 Af[3][4];                 // depth-2 prefetch ring
  auto loadA = [&](int g, bf16x8* fr) {
#pragma unroll
    for (int tm = 0; tm < 4; tm++)
      fr[tm] = *(const bf16x8*)(abase + ((size_t)(tm * 32 + g)) * 512);
  };

  loadA(0, Af[0]);
  loadA(1, Af[1]);
  stageB(0, Bs0);
  __syncthreads();

#pragma unroll
  for (int s = 0; s < 8; s++) {
    const unsigned short* bs = (s & 1) ? Bs1 : Bs0;
    if (s + 1 < 8) stageB((s + 1) * 128, (s & 1) ? Bs0 : Bs1);
#pragma unroll
    for (int sub = 0; sub < 4; sub++) {
      const int g = s * 4 + sub;
      if (g + 2 < 32) loadA(g + 2, Af[(g + 2) % 3]);
      const bf16x8* af = Af[g % 3];
#pragma unroll
      for (int tn = 0; tn < 8; tn++) {
        bf16x8 bfv = *(const bf16x8*)
            &bs[(sub * 4 + quad) * 1024 + (tn * 16 + l15) * 8];
#pragma unroll
        for (int tm = 0; tm < 4; tm++)
          acc[tm][tn] = __builtin_amdgcn_mfma_f32_16x16x32_bf16(
              af[tm], bfv, acc[tm][tn], 0, 0, 0);
      }
    }
    __syncthreads();
  }

  const int t3 = n0 >> 10;              // block-uniform: 0=Q,1=K,2=V
  if (t3 < 2) {
    // ---- Q/K scatter to head-major [b*h][t][d]
    unsigned short* dst0 = (t3 == 0) ? Qh : Kh;
    const float sc = (t3 == 0) ? 0.125f : 1.0f;   // 1/sqrt(64), exact
#pragma unroll
    for (int tm = 0; tm < 4; tm++)
#pragma unroll
      for (int tn = 0; tn < 8; tn++) {
        int colb = n0 + tn * 16;
        int hh = (colb >> 6) & 15;
        int dd = (colb & 63) + l15;
#pragma unroll
        for (int r = 0; r < 4; r++) {
          int row = m0 + w * 64 + tm * 16 + quad * 4 + r;
          int b = row >> 11, tt = row & 2047;
          dst0[((size_t)((b * 16 + hh) * 2048 + tt)) * 64 + dd] =
              f2bf(acc[tm][tn][r] * sc);
        }
      }
  } else {
    // ---- V: per-wave LDS transpose -> Vt [bh][tc][d 64][tin 64]
    unsigned short* T = (w < 3) ? (Bs0 + w * 4608) : Bs1;  // 64x72 tile
    const int b    = (m0 + w * 64) >> 11;
    const int tc_g = ((m0 & 2047) >> 6) + w;
    const int h0   = (n0 >> 6) & 15;
#pragma unroll
    for (int hp = 0; hp < 2; hp++) {
#pragma unroll
      for (int tnl = 0; tnl < 4; tnl++)
#pragma unroll
        for (int tm = 0; tm < 4; tm++)
#pragma unroll
          for (int r = 0; r < 4; r++)
            T[(tnl * 16 + l15) * 72 + tm * 16 + quad * 4 + r] =
                f2bf(acc[tm][hp * 4 + tnl][r]);
      asm volatile("s_waitcnt lgkmcnt(0)" ::: "memory");  // wave-private
      const size_t base =
          ((size_t)((b * 16 + h0 + hp) * 32 + tc_g)) * 4096;
#pragma unroll
      for (int i = 0; i < 8; i++) {
        int d   = i * 8 + (lane >> 3);
        int tin = (lane & 7) * 8;
        bf16x8 v = *(const bf16x8*)&T[d * 72 + tin];
        *(bf16x8*)&Vt[base + (size_t)d * 64 + tin] = v;   // coalesced 1KB
      }
    }
  }
}

// ---------------------------------------------------------------------------
// Proj GEMM (round 13): same L2-residency swizzle -- XCD owns 8 m-blocks
// (2 MB Ypk, L2-fits) x 8 n-panels; Wproj (2 MB) also L2-resident.
// ---------------------------------------------------------------------------
__global__ __launch_bounds__(256, 2)
void gemm_proj(const unsigned short* __restrict__ Apk,
               const unsigned short* __restrict__ Bw,
               float* __restrict__ Co) {
  __shared__ __align__(16) unsigned short Bs0[16 * 1024];
  __shared__ __align__(16) unsigned short Bs1[16 * 1024];

  const int id   = blockIdx.x;
  const int xcd  = id & 7;
  const int slot = id >> 3;        // 0..63
  const int mloc = slot >> 3;      // 0..7
  const int nloc = slot & 7;       // 0..7
  const int m0 = (xcd * 8 + mloc) * 128;
  const int n0 = nloc * 128;

  const int tid  = threadIdx.x;
  const int w    = tid >> 6;
  const int lane = tid & 63;
  const int quad = lane >> 4;
  const int l15  = lane & 15;

  f32x4 acc[2][8];
#pragma unroll
  for (int i = 0; i < 2; i++)
#pragma unroll
    for (int j = 0; j < 8; j++) acc[i][j] = (f32x4)0.0f;

  const unsigned short* abase =
      Apk + ((size_t)((m0 >> 4) + w * 2) * 32) * 512 + lane * 8;

  auto stageB = [&](int k0, unsigned short* bs) {
#pragma unroll
    for (int i = 0; i < 8; i++) {
      int idx  = w + 4 * i;
      int kc   = idx >> 1;
      int half = idx & 1;
      async_cp16(Bw + (size_t)(n0 + half * 64 + lane) * 1024 + k0 + kc * 8,
                 &bs[kc * 1024 + half * 512]);
    }
  };

  bf16x8 Af[3][2];                 // depth-2 prefetch ring
  auto loadA = [&](int g, bf16x8* fr) {
#pragma unroll
    for (int tm = 0; tm < 2; tm++)
      fr[tm] = *(const bf16x8*)(abase + ((size_t)(tm * 32 + g)) * 512);
  };

  loadA(0, Af[0]);
  loadA(1, Af[1]);
  stageB(0, Bs0);
  __syncthreads();

#pragma unroll
  for (int s = 0; s < 8; s++) {
    const unsigned short* bs = (s & 1) ? Bs1 : Bs0;
    if (s + 1 < 8) stageB((s + 1) * 128, (s & 1) ? Bs0 : Bs1);
#pragma unroll
    for (int sub = 0; sub < 4; sub++) {
      const int g = s * 4 + sub;
      if (g + 2 < 32) loadA(g + 2, Af[(g + 2) % 3]);
      const bf16x8* af = Af[g % 3];
#pragma unroll
      for (int tn = 0; tn < 8; tn++) {
        bf16x8 bfv = *(const bf16x8*)
            &bs[(sub * 4 + quad) * 1024 + (tn * 16 + l15) * 8];
#pragma unroll
        for (int tm = 0; tm < 2; tm++)
          acc[tm][tn] = __builtin_amdgcn_mfma_f32_16x16x32_bf16(
              af[tm], bfv, acc[tm][tn], 0, 0, 0);
      }
    }
    __syncthreads();
  }

#pragma unroll
  for (int tm = 0; tm < 2; tm++)
#pragma unroll
    for (int tn = 0; tn < 8; tn++)
#pragma unroll
      for (int r = 0; r < 4; r++) {
        int row = m0 + w * 32 + tm * 16 + quad * 4 + r;
        int col = n0 + tn * 16 + l15;
        Co[(size_t)row * 1024 + col] = acc[tm][tn][r];
      }
}

// ---------------------------------------------------------------------------
// MFMA sliding-window flash attention, single-stage (r9-validated).
// ---------------------------------------------------------------------------
__global__ __launch_bounds__(256, 2)
void attn_mfma(const unsigned short* __restrict__ Qh,
               const unsigned short* __restrict__ Kh,
               const unsigned short* __restrict__ Vt,
               unsigned short* __restrict__ Ypk) {
  __shared__ __align__(16) unsigned short SH[40960];   // 80 KB

  const int tid  = threadIdx.x;
  const int w    = tid >> 6;
  const int lane = tid & 63;
  const int quad = lane >> 4;
  const int l15  = lane & 15;
  const int q0 = blockIdx.x * 64;
  const int bh = blockIdx.y;

  const int c0 = (q0 >= 256) ? 0 : (4 - (q0 >> 6));

  const unsigned short* Qg = Qh + ((size_t)bh * 2048 + q0) * 64;
  bf16x8 Qf[2];
#pragma unroll
  for (int fs = 0; fs < 2; fs++)
    Qf[fs] = *(const bf16x8*)(Qg + (w * 16 + l15) * 64 + fs * 32 + quad * 8);

  const unsigned short* Kg = Kh + (size_t)bh * 2048 * 64;
  const unsigned short* Vg = Vt + (size_t)bh * 32 * 4096;
  for (int ch = c0; ch < 5; ch++) {
    int sc = q0 - 256 + ch * 64;
#pragma unroll
    for (int i = 0; i < 2; i++) {
      int kc = w * 2 + i;
      async_cp16(Kg + (size_t)(sc + lane) * 64 + kc * 8,
                 &SH[ch * 4096 + kc * 512]);
      async_cp16(Vg + (size_t)(sc >> 6) * 4096 + lane * 64 + kc * 8,
                 &SH[20480 + ch * 4096 + kc * 512]);
    }
  }
  __syncthreads();

  f32x4 S[5][4];
#pragma unroll
  for (int ch = 0; ch < 5; ch++)
#pragma unroll
    for (int tn = 0; tn < 4; tn++) S[ch][tn] = (f32x4)0.0f;

#pragma unroll
  for (int ch = 0; ch < 5; ch++) {
    if (ch < c0) continue;
#pragma unroll
    for (int ks = 0; ks < 2; ks++) {
      int kc = ks * 4 + quad;
#pragma unroll
      for (int tn = 0; tn < 4; tn++) {
        bf16x8 bk = *(const bf16x8*)
            &SH[ch * 4096 + kc * 512 + (tn * 16 + l15) * 8];
        S[ch][tn] = __builtin_amdgcn_mfma_f32_16x16x32_bf16(
            Qf[ks], bk, S[ch][tn], 0, 0, 0);
      }
    }
  }

  const int qb = q0 + w * 16 + quad * 4;
  if (c0 == 0) {
#pragma unroll
    for (int tn = 0; tn < 4; tn++) {
      int j = q0 - 256 + tn * 16 + l15;
#pragma unroll
      for (int r = 0; r < 4; r++)
        if (qb + r > j + (WW - 1)) S[0][tn][r] = -__builtin_inff();
    }
  }
#pragma unroll
  for (int tn = 0; tn < 4; tn++) {
    int j = q0 + tn * 16 + l15;
#pragma unroll
    for (int r = 0; r < 4; r++)
      if (j > qb + r) S[4][tn][r] = -__builtin_inff();
  }

  float mrow[4], lrow[4];
#pragma unroll
  for (int r = 0; r < 4; r++) mrow[r] = -__builtin_inff();
#pragma unroll
  for (int ch = 0; ch < 5; ch++) {
    if (ch < c0) continue;
#pragma unroll
    for (int tn = 0; tn < 4; tn++)
#pragma unroll
      for (int r = 0; r < 4; r++)
        mrow[r] = fmaxf(mrow[r], S[ch][tn][r]);
  }
#pragma unroll
  for (int off = 1; off < 16; off <<= 1)
#pragma unroll
    for (int r = 0; r < 4; r++)
      mrow[r] = fmaxf(mrow[r], __shfl_xor(mrow[r], off));

#pragma unroll
  for (int r = 0; r < 4; r++) lrow[r] = 0.0f;
#pragma unroll
  for (int ch = 0; ch < 5; ch++) {
    if (ch < c0) continue;
#pragma unroll
    for (int tn = 0; tn < 4; tn++)
#pragma unroll
      for (int r = 0; r < 4; r++) {
        float e = __expf(S[ch][tn][r] - mrow[r]);
        S[ch][tn][r] = e;
        lrow[r] += e;
      }
  }
#pragma unroll
  for (int off = 1; off < 16; off <<= 1)
#pragma unroll
    for (int r = 0; r < 4; r++) lrow[r] += __shfl_xor(lrow[r], off);

  __syncthreads();   // all K reads done before Ps aliases the K region

  f32x4 Oacc[4];
#pragma unroll
  for (int td = 0; td < 4; td++) Oacc[td] = (f32x4)0.0f;

#pragma unroll
  for (int ch = 0; ch < 5; ch++) {
    if (ch < c0) continue;
    unsigned short* Ps = SH + (ch & 1) * 4608;
#pragma unroll
    for (int tn = 0; tn < 4; tn++)
#pragma unroll
      for (int r = 0; r < 4; r++)
        Ps[(w * 16 + quad * 4 + r) * 68 + tn * 16 + l15] = f2bf(S[ch][tn][r]);
    asm volatile("s_waitcnt lgkmcnt(0)" ::: "memory");
#pragma unroll
    for (int ks = 0; ks < 2; ks++) {
      int off = (w * 16 + l15) * 68 + ks * 32 + quad * 8;
      bf16x4 plo = *(const bf16x4*)&Ps[off];
      bf16x4 phi = *(const bf16x4*)&Ps[off + 4];
      bf16x8 ap = __builtin_shufflevector(plo, phi, 0, 1, 2, 3, 4, 5, 6, 7);
      int kc = ks * 4 + quad;
#pragma unroll
      for (int td = 0; td < 4; td++) {
        bf16x8 bv = *(const bf16x8*)
            &SH[20480 + ch * 4096 + kc * 512 + (td * 16 + l15) * 8];
        Oacc[td] = __builtin_amdgcn_mfma_f32_16x16x32_bf16(
            ap, bv, Oacc[td], 0, 0, 0);
      }
    }
  }

  const int b = bh >> 4, h = bh & 15;
  float inv[4];
#pragma unroll
  for (int r = 0; r < 4; r++) inv[r] = 1.0f / lrow[r];
  unsigned short* Ot = SH + 10240;
#pragma unroll
  for (int td = 0; td < 4; td++)
#pragma unroll
    for (int r = 0; r < 4; r++)
      Ot[(w * 16 + quad * 4 + r) * 72 + td * 16 + l15] =
          f2bf(Oacc[td][r] * inv[r]);
  asm volatile("s_waitcnt lgkmcnt(0)" ::: "memory");
  const size_t rt = (size_t)((b * 2048 + q0) >> 4) + w;
#pragma unroll
  for (int f = 0; f < 2; f++) {
    bf16x8 fr = *(const bf16x8*)&Ot[(w * 16 + l15) * 72 + f * 32 + quad * 8];
    *(bf16x8*)&Ypk[(rt * 32 + h * 2 + f) * 512 + lane * 8] = fr;
  }
}

// ---------------------------------------------------------------------------
extern "C" void kernel_launch(void* const* d_in, const int* in_sizes, int n_in,
                              void* d_out, int out_size, void* d_ws, size_t ws_size,
                              hipStream_t stream) {
  const float* x     = (const float*)d_in[0];
  const float* wqkv  = (const float*)d_in[1];
  const float* wproj = (const float*)d_in[2];
  float* out = (float*)d_out;

  char* ws = (char*)d_ws;
  // [0,16M)   Apk (packed x)
  // [16,22M)  Wqkv bf16   [22,24M) Wproj bf16
  // [24,40M)  Qh   [40,56M) Kh   [56,72M) Vt   [72,88M) Ypk (packed y)
  unsigned short* apk    = (unsigned short*)(ws);
  unsigned short* wqkvb  = (unsigned short*)(ws + (size_t)16 * 1024 * 1024);
  unsigned short* wprojb = (unsigned short*)(ws + (size_t)22 * 1024 * 1024);
  unsigned short* qh     = (unsigned short*)(ws + (size_t)24 * 1024 * 1024);
  unsigned short* kh     = (unsigned short*)(ws + (size_t)40 * 1024 * 1024);
  unsigned short* vt     = (unsigned short*)(ws + (size_t)56 * 1024 * 1024);
  unsigned short* ypk    = (unsigned short*)(ws + (size_t)72 * 1024 * 1024);

  prep<<<4096 + 2048, 256, 0, stream>>>(
      x, wqkv, wproj, (__hip_bfloat16*)wqkvb, apk);

  // qkv = x @ Wqkv^T -> Qh/Kh (head-major) + Vt (transposed, fused)
  gemm_qkv<<<768, 256, 0, stream>>>(apk, wqkvb, qh, kh, vt);

  attn_mfma<<<dim3(TT / 64, BB * HH), 256, 0, stream>>>(
      qh, kh, vt, ypk);

  gemm_proj<<<512, 256, 0, stream>>>(ypk, wprojb, out);
}